// Round 1
// baseline (7565.342 us; speedup 1.0000x reference)
//
#include <hip/hip_runtime.h>
#include <hip/hip_bf16.h>

#define B_ 4
#define T_ 2048
#define C_ 768
#define H_ 12
#define D_ 64

// ---------------- LayerNorm (one block per row of 768) ----------------
__global__ __launch_bounds__(256) void ln_f32(const float* __restrict__ x,
                                              const float* __restrict__ g,
                                              const float* __restrict__ b,
                                              float* __restrict__ out) {
    int row = blockIdx.x;
    int tid = threadIdx.x;
    const float* xr = x + (size_t)row * C_;
    float v0 = xr[tid], v1 = xr[tid + 256], v2 = xr[tid + 512];
    float s = v0 + v1 + v2;
    #pragma unroll
    for (int off = 1; off < 64; off <<= 1) s += __shfl_xor(s, off);
    __shared__ float ws1[4], ws2[4];
    int wid = tid >> 6, lane = tid & 63;
    if (lane == 0) ws1[wid] = s;
    __syncthreads();
    float mean = (ws1[0] + ws1[1] + ws1[2] + ws1[3]) * (1.0f / C_);
    float d0 = v0 - mean, d1 = v1 - mean, d2 = v2 - mean;
    float qs = d0*d0 + d1*d1 + d2*d2;
    #pragma unroll
    for (int off = 1; off < 64; off <<= 1) qs += __shfl_xor(qs, off);
    if (lane == 0) ws2[wid] = qs;
    __syncthreads();
    float var = (ws2[0] + ws2[1] + ws2[2] + ws2[3]) * (1.0f / C_);
    float rs = rsqrtf(var + 1e-5f);
    float* orow = out + (size_t)row * C_;
    orow[tid]       = d0 * rs * g[tid]       + b[tid];
    orow[tid + 256] = d1 * rs * g[tid + 256] + b[tid + 256];
    orow[tid + 512] = d2 * rs * g[tid + 512] + b[tid + 512];
}

// ---------------- fp32 GEMM: C = A@B + bias (+epilogue) ----------------
// EPI: 0 = none, 1 = exact gelu, 2 = +resid
#define BM 64
#define BN 64
#define BK 16
template <int EPI>
__global__ __launch_bounds__(256) void gemm_f32(const float* __restrict__ A,
                                                const float* __restrict__ Bw,
                                                const float* __restrict__ bias,
                                                const float* __restrict__ resid,
                                                float* __restrict__ C,
                                                int M, int N, int K) {
    __shared__ float As[BK][BM + 4];  // transposed A tile, padded vs write conflicts
    __shared__ float Bs[BK][BN];
    int tid = threadIdx.x;
    int bm = blockIdx.y, bn = blockIdx.x;
    int tx = tid & 15, ty = tid >> 4;

    float acc[4][4];
    #pragma unroll
    for (int i = 0; i < 4; ++i)
        #pragma unroll
        for (int j = 0; j < 4; ++j) acc[i][j] = 0.0f;

    int arow = tid >> 2;          // 0..63
    int acol = (tid & 3) * 4;     // 0,4,8,12
    int brow = tid >> 4;          // 0..15
    int bcol = (tid & 15) * 4;    // 0..60
    const float* Ab = A + (size_t)(bm * BM) * K;
    const float* Bb = Bw + (size_t)bn * BN;

    for (int k0 = 0; k0 < K; k0 += BK) {
        float4 av = *(const float4*)(Ab + (size_t)arow * K + k0 + acol);
        float4 bv = *(const float4*)(Bb + (size_t)(k0 + brow) * N + bcol);
        As[acol + 0][arow] = av.x;
        As[acol + 1][arow] = av.y;
        As[acol + 2][arow] = av.z;
        As[acol + 3][arow] = av.w;
        *(float4*)&Bs[brow][bcol] = bv;
        __syncthreads();
        #pragma unroll
        for (int kk = 0; kk < BK; ++kk) {
            float4 a = *(const float4*)&As[kk][ty * 4];
            float4 b = *(const float4*)&Bs[kk][tx * 4];
            float af[4] = {a.x, a.y, a.z, a.w};
            float bf[4] = {b.x, b.y, b.z, b.w};
            #pragma unroll
            for (int i = 0; i < 4; ++i)
                #pragma unroll
                for (int j = 0; j < 4; ++j)
                    acc[i][j] = fmaf(af[i], bf[j], acc[i][j]);
        }
        __syncthreads();
    }

    int row0 = bm * BM + ty * 4;
    int col0 = bn * BN + tx * 4;
    #pragma unroll
    for (int i = 0; i < 4; ++i) {
        #pragma unroll
        for (int j = 0; j < 4; ++j) {
            float val = acc[i][j] + bias[col0 + j];
            if (EPI == 1) val = 0.5f * val * (1.0f + erff(val * 0.70710678118654752f));
            if (EPI == 2) val += resid[(size_t)(row0 + i) * N + col0 + j];
            C[(size_t)(row0 + i) * N + col0 + j] = val;
        }
    }
}

// ---------------- causal attention, online softmax ----------------
// 1 wave per query row; lane owns one k per tile of 64; per-lane O partials.
__global__ __launch_bounds__(256) void attn_f32(const float* __restrict__ Q,
                                                const float* __restrict__ K,
                                                const float* __restrict__ V,
                                                float* __restrict__ O) {
    int tid = threadIdx.x;
    int wid = tid >> 6, lane = tid & 63;
    int qb = blockIdx.x;                 // [0, B*H*T/4)
    int bh = qb / (T_ / 4);
    int qblk = qb % (T_ / 4);
    int b = bh / H_, h = bh % H_;
    int q = qblk * 4 + wid;

    __shared__ float qs[4][64];
    const size_t headoff = (size_t)h * D_;
    const float* qrow = Q + (size_t)(b * T_ + q) * C_ + headoff;
    qs[wid][lane] = qrow[lane];
    __syncthreads();

    float m = -INFINITY, l = 0.0f;
    float acc[64];
    #pragma unroll
    for (int d = 0; d < 64; ++d) acc[d] = 0.0f;

    const float* Kb = K + (size_t)b * T_ * C_ + headoff;
    const float* Vb = V + (size_t)b * T_ * C_ + headoff;
    int ntiles = q / 64 + 1;
    for (int kt = 0; kt < ntiles; ++kt) {
        int kk = kt * 64 + lane;
        const float4* k4 = (const float4*)(Kb + (size_t)kk * C_);
        float dot = 0.0f;
        #pragma unroll
        for (int d4 = 0; d4 < 16; ++d4) {
            float4 kv = k4[d4];
            float4 qv = *(const float4*)&qs[wid][d4 * 4];   // broadcast
            dot += qv.x * kv.x + qv.y * kv.y + qv.z * kv.z + qv.w * kv.w;
        }
        float s = (kk <= q) ? dot * 0.125f : -INFINITY;
        float mt = s;
        #pragma unroll
        for (int off = 1; off < 64; off <<= 1) mt = fmaxf(mt, __shfl_xor(mt, off));
        float mnew = fmaxf(m, mt);
        float scale = __expf(m - mnew);   // first iter: exp(-inf)=0
        float p = __expf(s - mnew);       // masked lanes: 0
        float ps = p;
        #pragma unroll
        for (int off = 1; off < 64; off <<= 1) ps += __shfl_xor(ps, off);
        l = l * scale + ps;
        m = mnew;
        const float4* v4 = (const float4*)(Vb + (size_t)kk * C_);
        #pragma unroll
        for (int d4 = 0; d4 < 16; ++d4) {
            float4 vv = v4[d4];
            acc[d4*4+0] = fmaf(acc[d4*4+0], scale, p * vv.x);
            acc[d4*4+1] = fmaf(acc[d4*4+1], scale, p * vv.y);
            acc[d4*4+2] = fmaf(acc[d4*4+2], scale, p * vv.z);
            acc[d4*4+3] = fmaf(acc[d4*4+3], scale, p * vv.w);
        }
    }

    float invl = 1.0f / l;
    float outv = 0.0f;
    #pragma unroll
    for (int d = 0; d < 64; ++d) {
        float t = acc[d];
        #pragma unroll
        for (int off = 1; off < 64; off <<= 1) t += __shfl_xor(t, off);
        if (lane == d) outv = t;
    }
    O[(size_t)(b * T_ + q) * C_ + headoff + lane] = outv * invl;
}

extern "C" void kernel_launch(void* const* d_in, const int* in_sizes, int n_in,
                              void* d_out, int out_size, void* d_ws, size_t ws_size,
                              hipStream_t stream) {
    const float* x   = (const float*)d_in[0];
    const float* Wq  = (const float*)d_in[1];
    const float* bq  = (const float*)d_in[2];
    const float* Wk  = (const float*)d_in[3];
    const float* bk  = (const float*)d_in[4];
    const float* Wv  = (const float*)d_in[5];
    const float* bv  = (const float*)d_in[6];
    const float* Wo  = (const float*)d_in[7];
    const float* bo  = (const float*)d_in[8];
    const float* g1  = (const float*)d_in[9];
    const float* b1  = (const float*)d_in[10];
    const float* g2  = (const float*)d_in[11];
    const float* b2  = (const float*)d_in[12];
    const float* W1  = (const float*)d_in[13];
    const float* bm1 = (const float*)d_in[14];
    const float* W2  = (const float*)d_in[15];
    const float* bm2 = (const float*)d_in[16];
    float* out = (float*)d_out;

    const size_t S = (size_t)B_ * T_ * C_;   // 6,291,456
    float* f = (float*)d_ws;
    float* h      = f;            // buf0; reused as attention out
    float* q      = f + S;        // buf1; reused as xmid
    float* k      = f + 2 * S;    // buf2; reused as ln2 out
    float* v      = f + 3 * S;    // buf3
    float* o      = h;
    float* xmid   = q;
    float* ln2h   = k;
    float* hidden = f + 3 * S;    // 4*S floats (overlaps dead v)

    const int M = B_ * T_;        // 8192
    dim3 blk(256);
    dim3 g_cc(C_ / BN, M / BM);           // (12, 128)
    dim3 g_c4(4 * C_ / BN, M / BM);       // (48, 128)

    ln_f32<<<dim3(M), blk, 0, stream>>>(x, g1, b1, h);
    gemm_f32<0><<<g_cc, blk, 0, stream>>>(h, Wq, bq, nullptr, q, M, C_, C_);
    gemm_f32<0><<<g_cc, blk, 0, stream>>>(h, Wk, bk, nullptr, k, M, C_, C_);
    gemm_f32<0><<<g_cc, blk, 0, stream>>>(h, Wv, bv, nullptr, v, M, C_, C_);
    attn_f32<<<dim3(B_ * H_ * T_ / 4), blk, 0, stream>>>(q, k, v, o);
    gemm_f32<2><<<g_cc, blk, 0, stream>>>(o, Wo, bo, x, xmid, M, C_, C_);
    ln_f32<<<dim3(M), blk, 0, stream>>>(xmid, g2, b2, ln2h);
    gemm_f32<1><<<g_c4, blk, 0, stream>>>(ln2h, W1, bm1, nullptr, hidden, M, 4 * C_, C_);
    gemm_f32<2><<<g_cc, blk, 0, stream>>>(hidden, W2, bm2, xmid, out, M, C_, 4 * C_);
}

// Round 2
// 2337.586 us; speedup vs baseline: 3.2364x; 3.2364x over previous
//
#include <hip/hip_runtime.h>
#include <hip/hip_bf16.h>

#define B_ 4
#define T_ 2048
#define C_ 768
#define H_ 12
#define D_ 64

// ---------------- LayerNorm (one block per row of 768) ----------------
__global__ __launch_bounds__(256) void ln_f32(const float* __restrict__ x,
                                              const float* __restrict__ g,
                                              const float* __restrict__ b,
                                              float* __restrict__ out) {
    int row = blockIdx.x;
    int tid = threadIdx.x;
    const float* xr = x + (size_t)row * C_;
    float v0 = xr[tid], v1 = xr[tid + 256], v2 = xr[tid + 512];
    float s = v0 + v1 + v2;
    #pragma unroll
    for (int off = 1; off < 64; off <<= 1) s += __shfl_xor(s, off);
    __shared__ float ws1[4], ws2[4];
    int wid = tid >> 6, lane = tid & 63;
    if (lane == 0) ws1[wid] = s;
    __syncthreads();
    float mean = (ws1[0] + ws1[1] + ws1[2] + ws1[3]) * (1.0f / C_);
    float d0 = v0 - mean, d1 = v1 - mean, d2 = v2 - mean;
    float qs = d0*d0 + d1*d1 + d2*d2;
    #pragma unroll
    for (int off = 1; off < 64; off <<= 1) qs += __shfl_xor(qs, off);
    if (lane == 0) ws2[wid] = qs;
    __syncthreads();
    float var = (ws2[0] + ws2[1] + ws2[2] + ws2[3]) * (1.0f / C_);
    float rs = rsqrtf(var + 1e-5f);
    float* orow = out + (size_t)row * C_;
    orow[tid]       = d0 * rs * g[tid]       + b[tid];
    orow[tid + 256] = d1 * rs * g[tid + 256] + b[tid + 256];
    orow[tid + 512] = d2 * rs * g[tid + 512] + b[tid + 512];
}

// ---------------- fp32 GEMM: C = A@B + bias (+epilogue) ----------------
// EPI: 0 = none, 1 = exact gelu, 2 = +resid
#define BM 64
#define BN 64
#define BK 16
template <int EPI>
__global__ __launch_bounds__(256) void gemm_f32(const float* __restrict__ A,
                                                const float* __restrict__ Bw,
                                                const float* __restrict__ bias,
                                                const float* __restrict__ resid,
                                                float* __restrict__ C,
                                                int M, int N, int K) {
    __shared__ float As[BK][BM + 4];
    __shared__ float Bs[BK][BN];
    int tid = threadIdx.x;
    int bm = blockIdx.y, bn = blockIdx.x;
    int tx = tid & 15, ty = tid >> 4;

    float acc[4][4];
    #pragma unroll
    for (int i = 0; i < 4; ++i)
        #pragma unroll
        for (int j = 0; j < 4; ++j) acc[i][j] = 0.0f;

    int arow = tid >> 2;
    int acol = (tid & 3) * 4;
    int brow = tid >> 4;
    int bcol = (tid & 15) * 4;
    const float* Ab = A + (size_t)(bm * BM) * K;
    const float* Bb = Bw + (size_t)bn * BN;

    for (int k0 = 0; k0 < K; k0 += BK) {
        float4 av = *(const float4*)(Ab + (size_t)arow * K + k0 + acol);
        float4 bv = *(const float4*)(Bb + (size_t)(k0 + brow) * N + bcol);
        As[acol + 0][arow] = av.x;
        As[acol + 1][arow] = av.y;
        As[acol + 2][arow] = av.z;
        As[acol + 3][arow] = av.w;
        *(float4*)&Bs[brow][bcol] = bv;
        __syncthreads();
        #pragma unroll
        for (int kk = 0; kk < BK; ++kk) {
            float4 a = *(const float4*)&As[kk][ty * 4];
            float4 b = *(const float4*)&Bs[kk][tx * 4];
            float af[4] = {a.x, a.y, a.z, a.w};
            float bf[4] = {b.x, b.y, b.z, b.w};
            #pragma unroll
            for (int i = 0; i < 4; ++i)
                #pragma unroll
                for (int j = 0; j < 4; ++j)
                    acc[i][j] = fmaf(af[i], bf[j], acc[i][j]);
        }
        __syncthreads();
    }

    int row0 = bm * BM + ty * 4;
    int col0 = bn * BN + tx * 4;
    #pragma unroll
    for (int i = 0; i < 4; ++i) {
        #pragma unroll
        for (int j = 0; j < 4; ++j) {
            float val = acc[i][j] + bias[col0 + j];
            if (EPI == 1) val = 0.5f * val * (1.0f + erff(val * 0.70710678118654752f));
            if (EPI == 2) val += resid[(size_t)(row0 + i) * N + col0 + j];
            C[(size_t)(row0 + i) * N + col0 + j] = val;
        }
    }
}

// ---------------- tiled flash attention (fp32, causal) ----------------
// One block per (b, h, 64-query tile). K/V tiles of 64 staged in LDS.
// S = Q@K^T and O += P@V as 4x4-microtile register GEMMs; online softmax
// with 16-lane shuffle row reductions. Only diagonal tile is masked.
__global__ __launch_bounds__(256) void attn_f32_tiled(const float* __restrict__ Q,
                                                      const float* __restrict__ K,
                                                      const float* __restrict__ V,
                                                      float* __restrict__ O) {
    __shared__ float Qs[64][68];   // [d][q]  (Q transposed)
    __shared__ float Ks[64][68];   // [d][k]  (K transposed)
    __shared__ float Vs[64][68];   // [k][d]
    __shared__ float Ps[64][68];   // [k][q]  (P transposed)

    int tid = threadIdx.x;
    int tx = tid & 15, ty = tid >> 4;   // ty in 0..15
    int qt = blockIdx.x % (T_ / 64);
    int bh = blockIdx.x / (T_ / 64);
    int b  = bh / H_, h = bh % H_;
    int q0 = qt * 64;
    const size_t hoff = (size_t)h * D_;

    int lr = tid >> 4;           // 0..15 (row within 16-row slab)
    int lc = (tid & 15) * 4;     // 0..60

    // stage Q tile transposed
    #pragma unroll
    for (int r = 0; r < 64; r += 16) {
        float4 qv = *(const float4*)(Q + (size_t)(b * T_ + q0 + lr + r) * C_ + hoff + lc);
        Qs[lc + 0][lr + r] = qv.x;
        Qs[lc + 1][lr + r] = qv.y;
        Qs[lc + 2][lr + r] = qv.z;
        Qs[lc + 3][lr + r] = qv.w;
    }

    float m[4], l[4], acc[4][4];
    #pragma unroll
    for (int i = 0; i < 4; ++i) {
        m[i] = -INFINITY;
        l[i] = 0.0f;
        #pragma unroll
        for (int d = 0; d < 4; ++d) acc[i][d] = 0.0f;
    }

    const float SCL = 0.125f * 1.44269504088896340736f;  // 1/sqrt(D) * log2(e)

    for (int kt = 0; kt <= qt; ++kt) {
        int k0 = kt * 64;
        __syncthreads();   // Ks/Vs/Ps free (prev PV done); Qs staged (iter 0)
        #pragma unroll
        for (int r = 0; r < 64; r += 16) {
            float4 kv = *(const float4*)(K + (size_t)(b * T_ + k0 + lr + r) * C_ + hoff + lc);
            Ks[lc + 0][lr + r] = kv.x;
            Ks[lc + 1][lr + r] = kv.y;
            Ks[lc + 2][lr + r] = kv.z;
            Ks[lc + 3][lr + r] = kv.w;
            *(float4*)&Vs[lr + r][lc] =
                *(const float4*)(V + (size_t)(b * T_ + k0 + lr + r) * C_ + hoff + lc);
        }
        __syncthreads();

        // S = Q @ K^T  (4x4 per thread over d=0..63)
        float s[4][4];
        #pragma unroll
        for (int i = 0; i < 4; ++i)
            #pragma unroll
            for (int j = 0; j < 4; ++j) s[i][j] = 0.0f;
        #pragma unroll 8
        for (int d = 0; d < 64; ++d) {
            float4 a  = *(const float4*)&Qs[d][ty * 4];
            float4 bv = *(const float4*)&Ks[d][tx * 4];
            float af[4] = {a.x, a.y, a.z, a.w};
            float bf[4] = {bv.x, bv.y, bv.z, bv.w};
            #pragma unroll
            for (int i = 0; i < 4; ++i)
                #pragma unroll
                for (int j = 0; j < 4; ++j)
                    s[i][j] = fmaf(af[i], bf[j], s[i][j]);
        }

        // online softmax (rows ty*4+i live in the 16-lane tx group)
        bool diag = (kt == qt);
        #pragma unroll
        for (int i = 0; i < 4; ++i) {
            int qi = ty * 4 + i;
            float rmax = -INFINITY;
            #pragma unroll
            for (int j = 0; j < 4; ++j) {
                float sv = s[i][j] * SCL;
                if (diag && (tx * 4 + j > qi)) sv = -INFINITY;
                s[i][j] = sv;
                rmax = fmaxf(rmax, sv);
            }
            #pragma unroll
            for (int off = 1; off < 16; off <<= 1) rmax = fmaxf(rmax, __shfl_xor(rmax, off));
            float mnew  = fmaxf(m[i], rmax);
            float scale = __builtin_amdgcn_exp2f(m[i] - mnew);   // first iter: 0
            float rsum = 0.0f;
            #pragma unroll
            for (int j = 0; j < 4; ++j) {
                float p = __builtin_amdgcn_exp2f(s[i][j] - mnew);
                s[i][j] = p;
                rsum += p;
            }
            #pragma unroll
            for (int off = 1; off < 16; off <<= 1) rsum += __shfl_xor(rsum, off);
            l[i] = l[i] * scale + rsum;
            m[i] = mnew;
            #pragma unroll
            for (int d = 0; d < 4; ++d) acc[i][d] *= scale;
        }

        // write P transposed: Ps[j][i]
        #pragma unroll
        for (int i = 0; i < 4; ++i)
            #pragma unroll
            for (int j = 0; j < 4; ++j)
                Ps[tx * 4 + j][ty * 4 + i] = s[i][j];
        __syncthreads();

        // O += P @ V
        #pragma unroll 8
        for (int j = 0; j < 64; ++j) {
            float4 a  = *(const float4*)&Ps[j][ty * 4];
            float4 bv = *(const float4*)&Vs[j][tx * 4];
            float af[4] = {a.x, a.y, a.z, a.w};
            float bf[4] = {bv.x, bv.y, bv.z, bv.w};
            #pragma unroll
            for (int i = 0; i < 4; ++i)
                #pragma unroll
                for (int d = 0; d < 4; ++d)
                    acc[i][d] = fmaf(af[i], bf[d], acc[i][d]);
        }
    }

    #pragma unroll
    for (int i = 0; i < 4; ++i) {
        float inv = 1.0f / l[i];
        float4 o4;
        o4.x = acc[i][0] * inv;
        o4.y = acc[i][1] * inv;
        o4.z = acc[i][2] * inv;
        o4.w = acc[i][3] * inv;
        *(float4*)(O + (size_t)(b * T_ + q0 + ty * 4 + i) * C_ + hoff + tx * 4) = o4;
    }
}

extern "C" void kernel_launch(void* const* d_in, const int* in_sizes, int n_in,
                              void* d_out, int out_size, void* d_ws, size_t ws_size,
                              hipStream_t stream) {
    const float* x   = (const float*)d_in[0];
    const float* Wq  = (const float*)d_in[1];
    const float* bq  = (const float*)d_in[2];
    const float* Wk  = (const float*)d_in[3];
    const float* bk  = (const float*)d_in[4];
    const float* Wv  = (const float*)d_in[5];
    const float* bv  = (const float*)d_in[6];
    const float* Wo  = (const float*)d_in[7];
    const float* bo  = (const float*)d_in[8];
    const float* g1  = (const float*)d_in[9];
    const float* b1  = (const float*)d_in[10];
    const float* g2  = (const float*)d_in[11];
    const float* b2  = (const float*)d_in[12];
    const float* W1  = (const float*)d_in[13];
    const float* bm1 = (const float*)d_in[14];
    const float* W2  = (const float*)d_in[15];
    const float* bm2 = (const float*)d_in[16];
    float* out = (float*)d_out;

    const size_t S = (size_t)B_ * T_ * C_;
    float* f = (float*)d_ws;
    float* h      = f;
    float* q      = f + S;
    float* k      = f + 2 * S;
    float* v      = f + 3 * S;
    float* o      = h;
    float* xmid   = q;
    float* ln2h   = k;
    float* hidden = f + 3 * S;

    const int M = B_ * T_;
    dim3 blk(256);
    dim3 g_cc(C_ / BN, M / BM);
    dim3 g_c4(4 * C_ / BN, M / BM);

    ln_f32<<<dim3(M), blk, 0, stream>>>(x, g1, b1, h);
    gemm_f32<0><<<g_cc, blk, 0, stream>>>(h, Wq, bq, nullptr, q, M, C_, C_);
    gemm_f32<0><<<g_cc, blk, 0, stream>>>(h, Wk, bk, nullptr, k, M, C_, C_);
    gemm_f32<0><<<g_cc, blk, 0, stream>>>(h, Wv, bv, nullptr, v, M, C_, C_);
    attn_f32_tiled<<<dim3(B_ * H_ * (T_ / 64)), blk, 0, stream>>>(q, k, v, o);
    gemm_f32<2><<<g_cc, blk, 0, stream>>>(o, Wo, bo, x, xmid, M, C_, C_);
    ln_f32<<<dim3(M), blk, 0, stream>>>(xmid, g2, b2, ln2h);
    gemm_f32<1><<<g_c4, blk, 0, stream>>>(ln2h, W1, bm1, nullptr, hidden, M, 4 * C_, C_);
    gemm_f32<2><<<g_cc, blk, 0, stream>>>(hidden, W2, bm2, xmid, out, M, C_, 4 * C_);
}

// Round 3
// 1078.936 us; speedup vs baseline: 7.0119x; 2.1666x over previous
//
#include <hip/hip_runtime.h>
#include <hip/hip_bf16.h>

#define B_ 4
#define T_ 2048
#define C_ 768
#define H_ 12
#define D_ 64

typedef __attribute__((ext_vector_type(8))) short short8;
typedef __attribute__((ext_vector_type(4))) float f32x4;

__device__ __forceinline__ unsigned short f2bf(float f) {
    __hip_bfloat16 h = __float2bfloat16(f);
    return *reinterpret_cast<unsigned short*>(&h);
}

__device__ __forceinline__ void gl_lds16(const void* g, void* l) {
    __builtin_amdgcn_global_load_lds((const __attribute__((address_space(1))) unsigned int*)g,
                                     (__attribute__((address_space(3))) unsigned int*)l,
                                     16, 0, 0);
}

// ---------------- LayerNorm: fp32 in, bf16 out ----------------
__global__ __launch_bounds__(256) void ln_f32_bf16(const float* __restrict__ x,
                                                   const float* __restrict__ g,
                                                   const float* __restrict__ b,
                                                   unsigned short* __restrict__ out) {
    int row = blockIdx.x;
    int tid = threadIdx.x;
    const float* xr = x + (size_t)row * C_;
    float v0 = xr[tid], v1 = xr[tid + 256], v2 = xr[tid + 512];
    float s = v0 + v1 + v2;
    #pragma unroll
    for (int off = 1; off < 64; off <<= 1) s += __shfl_xor(s, off);
    __shared__ float ws1[4], ws2[4];
    int wid = tid >> 6, lane = tid & 63;
    if (lane == 0) ws1[wid] = s;
    __syncthreads();
    float mean = (ws1[0] + ws1[1] + ws1[2] + ws1[3]) * (1.0f / C_);
    float d0 = v0 - mean, d1 = v1 - mean, d2 = v2 - mean;
    float qs = d0*d0 + d1*d1 + d2*d2;
    #pragma unroll
    for (int off = 1; off < 64; off <<= 1) qs += __shfl_xor(qs, off);
    if (lane == 0) ws2[wid] = qs;
    __syncthreads();
    float var = (ws2[0] + ws2[1] + ws2[2] + ws2[3]) * (1.0f / C_);
    float rs = rsqrtf(var + 1e-5f);
    unsigned short* orow = out + (size_t)row * C_;
    orow[tid]       = f2bf(d0 * rs * g[tid]       + b[tid]);
    orow[tid + 256] = f2bf(d1 * rs * g[tid + 256] + b[tid + 256]);
    orow[tid + 512] = f2bf(d2 * rs * g[tid + 512] + b[tid + 512]);
}

// ---------------- transpose + fp32->bf16 convert: Wt[n][k] = W[k][n] ----------------
__global__ __launch_bounds__(256) void transpose_bf16(const float* __restrict__ W,
                                                      unsigned short* __restrict__ Wt,
                                                      int K, int N) {
    __shared__ float t[64][65];
    int n0 = blockIdx.x * 64, k0 = blockIdx.y * 64;
    int r = threadIdx.x >> 4, c4 = (threadIdx.x & 15) * 4;
    #pragma unroll
    for (int i = 0; i < 4; ++i) {
        float4 v = *(const float4*)(W + (size_t)(k0 + i * 16 + r) * N + n0 + c4);
        t[i*16 + r][c4 + 0] = v.x;
        t[i*16 + r][c4 + 1] = v.y;
        t[i*16 + r][c4 + 2] = v.z;
        t[i*16 + r][c4 + 3] = v.w;
    }
    __syncthreads();
    #pragma unroll
    for (int i = 0; i < 4; ++i) {
        ushort4 o;
        o.x = f2bf(t[c4 + 0][i*16 + r]);
        o.y = f2bf(t[c4 + 1][i*16 + r]);
        o.z = f2bf(t[c4 + 2][i*16 + r]);
        o.w = f2bf(t[c4 + 3][i*16 + r]);
        *(ushort4*)(Wt + (size_t)(n0 + i * 16 + r) * K + k0 + c4) = o;
    }
}

// ---------------- bf16 MFMA GEMM (m97 structure): C = A @ Bt^T + bias ----------------
// A[M][K] bf16, Bt[N][K] bf16. 128x128 tile, BK=32, 4 waves 2x2, 4x4 frags each.
// EPI: 0 = fp32 out, 1 = gelu -> bf16 out, 2 = +resid -> fp32 out
template <int EPI>
__global__ __launch_bounds__(256) void gemm_bf16(const unsigned short* __restrict__ A,
                                                 const unsigned short* __restrict__ Bt,
                                                 const float* __restrict__ bias,
                                                 const float* __restrict__ resid,
                                                 void* __restrict__ Cout,
                                                 int M, int N, int K) {
    __shared__ short As[128 * 32];
    __shared__ short Bs[128 * 32];
    int tid = threadIdx.x;
    int w = tid >> 6, l = tid & 63;
    int bn = blockIdx.x, bm = blockIdx.y;
    int wr = w >> 1, wc = w & 1;

    f32x4 acc[4][4];
    #pragma unroll
    for (int m = 0; m < 4; ++m)
        #pragma unroll
        for (int n = 0; n < 4; ++n)
            acc[m][n] = (f32x4){0.f, 0.f, 0.f, 0.f};

    const short* Ag = (const short*)A + (size_t)(bm * 128) * K;
    const short* Bg = (const short*)Bt + (size_t)(bn * 128) * K;
    int srow = tid >> 2;           // 0..63
    int scol = (tid & 3) * 8;      // element col within K-tile
    int lrow = l & 15, lk = (l >> 4) * 8;

    int nk = K / 32;
    for (int kt = 0; kt < nk; ++kt) {
        int k0 = kt * 32;
        if (kt > 0) __syncthreads();   // prior ds_reads done before overwrite
        #pragma unroll
        for (int i = 0; i < 2; ++i) {
            // lds dest: wave-uniform base; HW adds lane*16B. Linear [row][32] layout.
            gl_lds16(Ag + (size_t)(i * 64 + srow) * K + k0 + scol,
                     (char*)As + i * 4096 + w * 1024);
            gl_lds16(Bg + (size_t)(i * 64 + srow) * K + k0 + scol,
                     (char*)Bs + i * 4096 + w * 1024);
        }
        __syncthreads();               // drains vmcnt -> staged data visible

        short8 av[4], bv[4];
        #pragma unroll
        for (int m = 0; m < 4; ++m)
            av[m] = *(const short8*)&As[(wr * 64 + m * 16 + lrow) * 32 + lk];
        #pragma unroll
        for (int n = 0; n < 4; ++n)
            bv[n] = *(const short8*)&Bs[(wc * 64 + n * 16 + lrow) * 32 + lk];
        #pragma unroll
        for (int m = 0; m < 4; ++m)
            #pragma unroll
            for (int n = 0; n < 4; ++n)
                acc[m][n] = __builtin_amdgcn_mfma_f32_16x16x32_bf16(av[m], bv[n], acc[m][n], 0, 0, 0);
    }

    // epilogue — C/D layout: col = l&15, row = (l>>4)*4 + reg  [m89-verified]
    int lcol = l & 15, lr4 = (l >> 4) * 4;
    int row0 = bm * 128 + wr * 64;
    int col0 = bn * 128 + wc * 64;
    #pragma unroll
    for (int m = 0; m < 4; ++m) {
        #pragma unroll
        for (int n = 0; n < 4; ++n) {
            int col = col0 + n * 16 + lcol;
            float bz = bias[col];
            #pragma unroll
            for (int r = 0; r < 4; ++r) {
                int row = row0 + m * 16 + lr4 + r;
                float v = acc[m][n][r] + bz;
                if (EPI == 0) {
                    ((float*)Cout)[(size_t)row * N + col] = v;
                } else if (EPI == 1) {
                    v = 0.5f * v * (1.0f + erff(v * 0.70710678118654752f));
                    ((unsigned short*)Cout)[(size_t)row * N + col] = f2bf(v);
                } else {
                    v += resid[(size_t)row * N + col];
                    ((float*)Cout)[(size_t)row * N + col] = v;
                }
            }
        }
    }
}

// ---------------- tiled flash attention (fp32 math, bf16 out, causal) ----------------
__global__ __launch_bounds__(256) void attn_f32_tiled(const float* __restrict__ Q,
                                                      const float* __restrict__ K,
                                                      const float* __restrict__ V,
                                                      unsigned short* __restrict__ O) {
    __shared__ float Qs[64][68];
    __shared__ float Ks[64][68];
    __shared__ float Vs[64][68];
    __shared__ float Ps[64][68];

    int tid = threadIdx.x;
    int tx = tid & 15, ty = tid >> 4;
    int qt = blockIdx.x % (T_ / 64);
    int bh = blockIdx.x / (T_ / 64);
    int b  = bh / H_, h = bh % H_;
    int q0 = qt * 64;
    const size_t hoff = (size_t)h * D_;

    int lr = tid >> 4;
    int lc = (tid & 15) * 4;

    #pragma unroll
    for (int r = 0; r < 64; r += 16) {
        float4 qv = *(const float4*)(Q + (size_t)(b * T_ + q0 + lr + r) * C_ + hoff + lc);
        Qs[lc + 0][lr + r] = qv.x;
        Qs[lc + 1][lr + r] = qv.y;
        Qs[lc + 2][lr + r] = qv.z;
        Qs[lc + 3][lr + r] = qv.w;
    }

    float m[4], l[4], acc[4][4];
    #pragma unroll
    for (int i = 0; i < 4; ++i) {
        m[i] = -INFINITY;
        l[i] = 0.0f;
        #pragma unroll
        for (int d = 0; d < 4; ++d) acc[i][d] = 0.0f;
    }

    const float SCL = 0.125f * 1.44269504088896340736f;

    for (int kt = 0; kt <= qt; ++kt) {
        int k0 = kt * 64;
        __syncthreads();
        #pragma unroll
        for (int r = 0; r < 64; r += 16) {
            float4 kv = *(const float4*)(K + (size_t)(b * T_ + k0 + lr + r) * C_ + hoff + lc);
            Ks[lc + 0][lr + r] = kv.x;
            Ks[lc + 1][lr + r] = kv.y;
            Ks[lc + 2][lr + r] = kv.z;
            Ks[lc + 3][lr + r] = kv.w;
            *(float4*)&Vs[lr + r][lc] =
                *(const float4*)(V + (size_t)(b * T_ + k0 + lr + r) * C_ + hoff + lc);
        }
        __syncthreads();

        float s[4][4];
        #pragma unroll
        for (int i = 0; i < 4; ++i)
            #pragma unroll
            for (int j = 0; j < 4; ++j) s[i][j] = 0.0f;
        #pragma unroll 8
        for (int d = 0; d < 64; ++d) {
            float4 a  = *(const float4*)&Qs[d][ty * 4];
            float4 bv = *(const float4*)&Ks[d][tx * 4];
            float af[4] = {a.x, a.y, a.z, a.w};
            float bf[4] = {bv.x, bv.y, bv.z, bv.w};
            #pragma unroll
            for (int i = 0; i < 4; ++i)
                #pragma unroll
                for (int j = 0; j < 4; ++j)
                    s[i][j] = fmaf(af[i], bf[j], s[i][j]);
        }

        bool diag = (kt == qt);
        #pragma unroll
        for (int i = 0; i < 4; ++i) {
            int qi = ty * 4 + i;
            float rmax = -INFINITY;
            #pragma unroll
            for (int j = 0; j < 4; ++j) {
                float sv = s[i][j] * SCL;
                if (diag && (tx * 4 + j > qi)) sv = -INFINITY;
                s[i][j] = sv;
                rmax = fmaxf(rmax, sv);
            }
            #pragma unroll
            for (int off = 1; off < 16; off <<= 1) rmax = fmaxf(rmax, __shfl_xor(rmax, off));
            float mnew  = fmaxf(m[i], rmax);
            float scale = __builtin_amdgcn_exp2f(m[i] - mnew);
            float rsum = 0.0f;
            #pragma unroll
            for (int j = 0; j < 4; ++j) {
                float p = __builtin_amdgcn_exp2f(s[i][j] - mnew);
                s[i][j] = p;
                rsum += p;
            }
            #pragma unroll
            for (int off = 1; off < 16; off <<= 1) rsum += __shfl_xor(rsum, off);
            l[i] = l[i] * scale + rsum;
            m[i] = mnew;
            #pragma unroll
            for (int d = 0; d < 4; ++d) acc[i][d] *= scale;
        }

        #pragma unroll
        for (int i = 0; i < 4; ++i)
            #pragma unroll
            for (int j = 0; j < 4; ++j)
                Ps[tx * 4 + j][ty * 4 + i] = s[i][j];
        __syncthreads();

        #pragma unroll 8
        for (int j = 0; j < 64; ++j) {
            float4 a  = *(const float4*)&Ps[j][ty * 4];
            float4 bv = *(const float4*)&Vs[j][tx * 4];
            float af[4] = {a.x, a.y, a.z, a.w};
            float bf[4] = {bv.x, bv.y, bv.z, bv.w};
            #pragma unroll
            for (int i = 0; i < 4; ++i)
                #pragma unroll
                for (int d = 0; d < 4; ++d)
                    acc[i][d] = fmaf(af[i], bf[d], acc[i][d]);
        }
    }

    #pragma unroll
    for (int i = 0; i < 4; ++i) {
        float inv = 1.0f / l[i];
        ushort4 o4;
        o4.x = f2bf(acc[i][0] * inv);
        o4.y = f2bf(acc[i][1] * inv);
        o4.z = f2bf(acc[i][2] * inv);
        o4.w = f2bf(acc[i][3] * inv);
        *(ushort4*)(O + (size_t)(b * T_ + q0 + ty * 4 + i) * C_ + hoff + tx * 4) = o4;
    }
}

extern "C" void kernel_launch(void* const* d_in, const int* in_sizes, int n_in,
                              void* d_out, int out_size, void* d_ws, size_t ws_size,
                              hipStream_t stream) {
    const float* x   = (const float*)d_in[0];
    const float* Wq  = (const float*)d_in[1];
    const float* bq  = (const float*)d_in[2];
    const float* Wk  = (const float*)d_in[3];
    const float* bk  = (const float*)d_in[4];
    const float* Wv  = (const float*)d_in[5];
    const float* bv  = (const float*)d_in[6];
    const float* Wo  = (const float*)d_in[7];
    const float* bo  = (const float*)d_in[8];
    const float* g1  = (const float*)d_in[9];
    const float* b1  = (const float*)d_in[10];
    const float* g2  = (const float*)d_in[11];
    const float* b2  = (const float*)d_in[12];
    const float* W1  = (const float*)d_in[13];
    const float* bm1 = (const float*)d_in[14];
    const float* W2  = (const float*)d_in[15];
    const float* bm2 = (const float*)d_in[16];
    float* out = (float*)d_out;

    const size_t S = (size_t)B_ * T_ * C_;            // 6,291,456
    char* base = (char*)d_ws;
    // layout (bytes): [0, 2S) ln1h/o bf16 | [2S, 6S) q f32 | [6S, 10S) k f32 |
    //                 [10S, 18S) v f32 + hidden bf16 (4S elems) | [18S, ...) weights bf16
    unsigned short* ln1h = (unsigned short*)base;                 // also attn out 'o'
    float* qb   = (float*)(base + 2 * S);
    float* kb   = (float*)(base + 6 * S);
    float* vb   = (float*)(base + 10 * S);
    unsigned short* o    = ln1h;
    float* xmid          = qb;                                     // q dead after attn
    unsigned short* ln2h = (unsigned short*)kb;                    // k dead after attn
    unsigned short* hid  = (unsigned short*)vb;                    // v dead after attn
    unsigned short* wqt  = (unsigned short*)(base + 18 * S);
    unsigned short* wkt  = wqt + (size_t)C_ * C_;
    unsigned short* wvt  = wkt + (size_t)C_ * C_;
    unsigned short* wot  = wvt + (size_t)C_ * C_;
    unsigned short* w1t  = wot + (size_t)C_ * C_;                  // [3072][768]
    unsigned short* w2t  = w1t + (size_t)C_ * 4 * C_;              // [768][3072]

    const int M = B_ * T_;   // 8192
    dim3 blk(256);

    transpose_bf16<<<dim3(C_ / 64, C_ / 64), blk, 0, stream>>>(Wq, wqt, C_, C_);
    transpose_bf16<<<dim3(C_ / 64, C_ / 64), blk, 0, stream>>>(Wk, wkt, C_, C_);
    transpose_bf16<<<dim3(C_ / 64, C_ / 64), blk, 0, stream>>>(Wv, wvt, C_, C_);
    transpose_bf16<<<dim3(C_ / 64, C_ / 64), blk, 0, stream>>>(Wo, wot, C_, C_);
    transpose_bf16<<<dim3(4 * C_ / 64, C_ / 64), blk, 0, stream>>>(W1, w1t, C_, 4 * C_);
    transpose_bf16<<<dim3(C_ / 64, 4 * C_ / 64), blk, 0, stream>>>(W2, w2t, 4 * C_, C_);

    ln_f32_bf16<<<dim3(M), blk, 0, stream>>>(x, g1, b1, ln1h);

    dim3 g_cc(C_ / 128, M / 128);        // (6, 64)
    dim3 g_c4(4 * C_ / 128, M / 128);    // (24, 64)
    gemm_bf16<0><<<g_cc, blk, 0, stream>>>(ln1h, wqt, bq, nullptr, qb, M, C_, C_);
    gemm_bf16<0><<<g_cc, blk, 0, stream>>>(ln1h, wkt, bk, nullptr, kb, M, C_, C_);
    gemm_bf16<0><<<g_cc, blk, 0, stream>>>(ln1h, wvt, bv, nullptr, vb, M, C_, C_);

    attn_f32_tiled<<<dim3(B_ * H_ * (T_ / 64)), blk, 0, stream>>>(qb, kb, vb, o);

    gemm_bf16<2><<<g_cc, blk, 0, stream>>>(o, wot, bo, x, xmid, M, C_, C_);
    ln_f32_bf16<<<dim3(M), blk, 0, stream>>>(xmid, g2, b2, ln2h);
    gemm_bf16<1><<<g_c4, blk, 0, stream>>>(ln2h, w1t, bm1, nullptr, hid, M, 4 * C_, C_);
    gemm_bf16<2><<<g_cc, blk, 0, stream>>>(hid, w2t, bm2, xmid, out, M, C_, 4 * C_);
}

// Round 4
// 481.966 us; speedup vs baseline: 15.6968x; 2.2386x over previous
//
#include <hip/hip_runtime.h>
#include <hip/hip_bf16.h>

#define B_ 4
#define T_ 2048
#define C_ 768
#define H_ 12
#define D_ 64

typedef __attribute__((ext_vector_type(8))) short short8;
typedef __attribute__((ext_vector_type(4))) short short4v;
typedef __attribute__((ext_vector_type(4))) float f32x4;

__device__ __forceinline__ unsigned short f2bf(float f) {
    __hip_bfloat16 h = __float2bfloat16(f);
    return *reinterpret_cast<unsigned short*>(&h);
}

__device__ __forceinline__ void gl_lds16(const void* g, void* l) {
    __builtin_amdgcn_global_load_lds((const __attribute__((address_space(1))) unsigned int*)g,
                                     (__attribute__((address_space(3))) unsigned int*)l,
                                     16, 0, 0);
}

// ---------------- LayerNorm: fp32 in, bf16 out ----------------
__global__ __launch_bounds__(256) void ln_f32_bf16(const float* __restrict__ x,
                                                   const float* __restrict__ g,
                                                   const float* __restrict__ b,
                                                   unsigned short* __restrict__ out) {
    int row = blockIdx.x;
    int tid = threadIdx.x;
    const float* xr = x + (size_t)row * C_;
    float v0 = xr[tid], v1 = xr[tid + 256], v2 = xr[tid + 512];
    float s = v0 + v1 + v2;
    #pragma unroll
    for (int off = 1; off < 64; off <<= 1) s += __shfl_xor(s, off);
    __shared__ float ws1[4], ws2[4];
    int wid = tid >> 6, lane = tid & 63;
    if (lane == 0) ws1[wid] = s;
    __syncthreads();
    float mean = (ws1[0] + ws1[1] + ws1[2] + ws1[3]) * (1.0f / C_);
    float d0 = v0 - mean, d1 = v1 - mean, d2 = v2 - mean;
    float qs = d0*d0 + d1*d1 + d2*d2;
    #pragma unroll
    for (int off = 1; off < 64; off <<= 1) qs += __shfl_xor(qs, off);
    if (lane == 0) ws2[wid] = qs;
    __syncthreads();
    float var = (ws2[0] + ws2[1] + ws2[2] + ws2[3]) * (1.0f / C_);
    float rs = rsqrtf(var + 1e-5f);
    unsigned short* orow = out + (size_t)row * C_;
    orow[tid]       = f2bf(d0 * rs * g[tid]       + b[tid]);
    orow[tid + 256] = f2bf(d1 * rs * g[tid + 256] + b[tid + 256]);
    orow[tid + 512] = f2bf(d2 * rs * g[tid + 512] + b[tid + 512]);
}

// ---------------- transpose + fp32->bf16 convert: Wt[n][k] = W[k][n] ----------------
__global__ __launch_bounds__(256) void transpose_bf16(const float* __restrict__ W,
                                                      unsigned short* __restrict__ Wt,
                                                      int K, int N) {
    __shared__ float t[64][65];
    int n0 = blockIdx.x * 64, k0 = blockIdx.y * 64;
    int r = threadIdx.x >> 4, c4 = (threadIdx.x & 15) * 4;
    #pragma unroll
    for (int i = 0; i < 4; ++i) {
        float4 v = *(const float4*)(W + (size_t)(k0 + i * 16 + r) * N + n0 + c4);
        t[i*16 + r][c4 + 0] = v.x;
        t[i*16 + r][c4 + 1] = v.y;
        t[i*16 + r][c4 + 2] = v.z;
        t[i*16 + r][c4 + 3] = v.w;
    }
    __syncthreads();
    #pragma unroll
    for (int i = 0; i < 4; ++i) {
        ushort4 o;
        o.x = f2bf(t[c4 + 0][i*16 + r]);
        o.y = f2bf(t[c4 + 1][i*16 + r]);
        o.z = f2bf(t[c4 + 2][i*16 + r]);
        o.w = f2bf(t[c4 + 3][i*16 + r]);
        *(ushort4*)(Wt + (size_t)(n0 + i * 16 + r) * K + k0 + c4) = o;
    }
}

// ---------------- bf16 MFMA GEMM: C = A @ Bt^T + bias ----------------
// EPI: 1 = gelu -> bf16 out, 2 = +resid -> fp32 out, 3 = bf16 out
template <int EPI>
__global__ __launch_bounds__(256) void gemm_bf16(const unsigned short* __restrict__ A,
                                                 const unsigned short* __restrict__ Bt,
                                                 const float* __restrict__ bias,
                                                 const float* __restrict__ resid,
                                                 void* __restrict__ Cout,
                                                 int M, int N, int K) {
    __shared__ short As[128 * 32];
    __shared__ short Bs[128 * 32];
    int tid = threadIdx.x;
    int w = tid >> 6, l = tid & 63;
    int bn = blockIdx.x, bm = blockIdx.y;
    int wr = w >> 1, wc = w & 1;

    f32x4 acc[4][4];
    #pragma unroll
    for (int m = 0; m < 4; ++m)
        #pragma unroll
        for (int n = 0; n < 4; ++n)
            acc[m][n] = (f32x4){0.f, 0.f, 0.f, 0.f};

    const short* Ag = (const short*)A + (size_t)(bm * 128) * K;
    const short* Bg = (const short*)Bt + (size_t)(bn * 128) * K;
    int srow = tid >> 2;
    int scol = (tid & 3) * 8;
    int lrow = l & 15, lk = (l >> 4) * 8;

    int nk = K / 32;
    for (int kt = 0; kt < nk; ++kt) {
        int k0 = kt * 32;
        if (kt > 0) __syncthreads();
        #pragma unroll
        for (int i = 0; i < 2; ++i) {
            gl_lds16(Ag + (size_t)(i * 64 + srow) * K + k0 + scol,
                     (char*)As + i * 4096 + w * 1024);
            gl_lds16(Bg + (size_t)(i * 64 + srow) * K + k0 + scol,
                     (char*)Bs + i * 4096 + w * 1024);
        }
        __syncthreads();

        short8 av[4], bv[4];
        #pragma unroll
        for (int m = 0; m < 4; ++m)
            av[m] = *(const short8*)&As[(wr * 64 + m * 16 + lrow) * 32 + lk];
        #pragma unroll
        for (int n = 0; n < 4; ++n)
            bv[n] = *(const short8*)&Bs[(wc * 64 + n * 16 + lrow) * 32 + lk];
        #pragma unroll
        for (int m = 0; m < 4; ++m)
            #pragma unroll
            for (int n = 0; n < 4; ++n)
                acc[m][n] = __builtin_amdgcn_mfma_f32_16x16x32_bf16(av[m], bv[n], acc[m][n], 0, 0, 0);
    }

    int lcol = l & 15, lr4 = (l >> 4) * 4;
    int row0 = bm * 128 + wr * 64;
    int col0 = bn * 128 + wc * 64;
    #pragma unroll
    for (int m = 0; m < 4; ++m) {
        #pragma unroll
        for (int n = 0; n < 4; ++n) {
            int col = col0 + n * 16 + lcol;
            float bz = bias[col];
            #pragma unroll
            for (int r = 0; r < 4; ++r) {
                int row = row0 + m * 16 + lr4 + r;
                float v = acc[m][n][r] + bz;
                if (EPI == 1) {
                    v = 0.5f * v * (1.0f + erff(v * 0.70710678118654752f));
                    ((unsigned short*)Cout)[(size_t)row * N + col] = f2bf(v);
                } else if (EPI == 2) {
                    v += resid[(size_t)row * N + col];
                    ((float*)Cout)[(size_t)row * N + col] = v;
                } else {
                    ((unsigned short*)Cout)[(size_t)row * N + col] = f2bf(v);
                }
            }
        }
    }
}

// ---------------- MFMA flash attention (bf16 in/out, fp32 accum, causal) ----------------
// Block = (b, h, 128-q tile). 4 waves x 32 q-rows. K-tile 64 in swizzled LDS;
// V transposed [d][k] in swizzled LDS; P via per-wave swizzled LDS.
__global__ __launch_bounds__(256) void attn_mfma(const unsigned short* __restrict__ Q,
                                                 const unsigned short* __restrict__ K,
                                                 const unsigned short* __restrict__ V,
                                                 unsigned short* __restrict__ O) {
    __shared__ short Ks[64 * 64];
    __shared__ short Vt[64 * 64];
    __shared__ short Ps[4][32 * 64];

    int tid = threadIdx.x;
    int w = tid >> 6, l = tid & 63;
    int g = l >> 4, lc = l & 15;
    int qt = (T_ / 128 - 1) - (int)(blockIdx.x & 15);   // heavy tiles first
    int bh = blockIdx.x >> 4;
    int b = bh / H_, h = bh % H_;
    int q0 = qt * 128;
    const size_t hoff = (size_t)h * D_;
    const size_t bT = (size_t)b * T_;

    // Q fragments: A-operand row = l&15, k-cols = g*8 (+ks*32)
    short8 qf[2][2];
    #pragma unroll
    for (int m = 0; m < 2; ++m) {
        int row = q0 + w * 32 + m * 16 + lc;
        const unsigned short* qp = Q + (bT + row) * C_ + hoff;
        #pragma unroll
        for (int ks = 0; ks < 2; ++ks)
            qf[m][ks] = *(const short8*)(qp + ks * 32 + g * 8);
    }

    f32x4 oacc[2][4];
    float mrun[2][4], lrun[2][4];
    #pragma unroll
    for (int m = 0; m < 2; ++m) {
        #pragma unroll
        for (int n = 0; n < 4; ++n) oacc[m][n] = (f32x4){0.f, 0.f, 0.f, 0.f};
        #pragma unroll
        for (int r = 0; r < 4; ++r) { mrun[m][r] = -INFINITY; lrun[m][r] = 0.f; }
    }

    const float SCL = 0.125f * 1.44269504088896340736f;  // 1/sqrt(D) * log2(e)
    int ntiles = 2 * qt + 2;

    for (int kt = 0; kt < ntiles; ++kt) {
        int k0 = kt * 64;
        if (kt) __syncthreads();   // all waves done reading Ks/Vt of prev tile
        // stage K [64][64] bf16, XOR-swizzled: byte ^= (row&7)<<4
        #pragma unroll
        for (int p = 0; p < 2; ++p) {
            int kk = p * 32 + (tid >> 3);
            int ce = (tid & 7) * 8;
            short8 kv = *(const short8*)(K + (bT + k0 + kk) * C_ + hoff + ce);
            int byt = (kk * 128 + ce * 2) ^ ((kk & 7) << 4);
            *(short8*)((char*)Ks + byt) = kv;
        }
        // stage V transposed: Vt[d][k]; coalesced 128B row reads, swizzled b64 writes
        {
            int d = l;
            #pragma unroll
            for (int p = 0; p < 4; ++p) {
                int kk0 = w * 16 + p * 4;
                const unsigned short* vp = V + (bT + k0 + kk0) * C_ + hoff + d;
                unsigned short t0 = vp[0];
                unsigned short t1 = vp[C_];
                unsigned short t2 = vp[2 * C_];
                unsigned short t3 = vp[3 * C_];
                short4v pk = {(short)t0, (short)t1, (short)t2, (short)t3};
                int byt = (d * 128 + kk0 * 2) ^ ((d & 7) << 4);
                *(short4v*)((char*)Vt + byt) = pk;
            }
        }
        __syncthreads();

        // S = Q @ K^T
        f32x4 sacc[2][4];
        #pragma unroll
        for (int m = 0; m < 2; ++m)
            #pragma unroll
            for (int n = 0; n < 4; ++n) sacc[m][n] = (f32x4){0.f, 0.f, 0.f, 0.f};
        #pragma unroll
        for (int ks = 0; ks < 2; ++ks) {
            short8 bv[4];
            #pragma unroll
            for (int n = 0; n < 4; ++n) {
                int row = n * 16 + lc;
                int byt = (row * 128 + ks * 64 + g * 16) ^ ((row & 7) << 4);
                bv[n] = *(const short8*)((char*)Ks + byt);
            }
            #pragma unroll
            for (int m = 0; m < 2; ++m)
                #pragma unroll
                for (int n = 0; n < 4; ++n)
                    sacc[m][n] = __builtin_amdgcn_mfma_f32_16x16x32_bf16(qf[m][ks], bv[n], sacc[m][n], 0, 0, 0);
        }

        // scale + causal mask (only partial tiles)
        bool full = (k0 + 63 <= q0 + w * 32);
        #pragma unroll
        for (int m = 0; m < 2; ++m) {
            #pragma unroll
            for (int n = 0; n < 4; ++n) {
                int col = k0 + n * 16 + lc;
                #pragma unroll
                for (int r = 0; r < 4; ++r) {
                    float sv = sacc[m][n][r] * SCL;
                    if (!full && col > q0 + w * 32 + m * 16 + g * 4 + r) sv = -INFINITY;
                    sacc[m][n][r] = sv;
                }
            }
        }

        // online softmax per (m, r); row lives in the 16-lane column group
        #pragma unroll
        for (int m = 0; m < 2; ++m) {
            #pragma unroll
            for (int r = 0; r < 4; ++r) {
                float rm = fmaxf(fmaxf(sacc[m][0][r], sacc[m][1][r]),
                                 fmaxf(sacc[m][2][r], sacc[m][3][r]));
                #pragma unroll
                for (int off = 1; off < 16; off <<= 1) rm = fmaxf(rm, __shfl_xor(rm, off));
                float mnew = fmaxf(mrun[m][r], rm);
                float sc = __builtin_amdgcn_exp2f(mrun[m][r] - mnew);  // first tile: 0
                float rs = 0.f;
                #pragma unroll
                for (int n = 0; n < 4; ++n) {
                    float p = __builtin_amdgcn_exp2f(sacc[m][n][r] - mnew);
                    sacc[m][n][r] = p;
                    rs += p;
                }
                #pragma unroll
                for (int off = 1; off < 16; off <<= 1) rs += __shfl_xor(rs, off);
                lrun[m][r] = lrun[m][r] * sc + rs;
                mrun[m][r] = mnew;
                #pragma unroll
                for (int n = 0; n < 4; ++n) oacc[m][n][r] *= sc;
            }
        }

        // write P (bf16) to per-wave swizzled LDS
        char* pw = (char*)&Ps[w][0];
        #pragma unroll
        for (int m = 0; m < 2; ++m)
            #pragma unroll
            for (int n = 0; n < 4; ++n)
                #pragma unroll
                for (int r = 0; r < 4; ++r) {
                    int prow = m * 16 + g * 4 + r;
                    int byt = (prow * 128 + (n * 16 + lc) * 2) ^ ((prow & 7) << 4);
                    *(unsigned short*)(pw + byt) = f2bf(sacc[m][n][r]);
                }

        // O += P @ V  (same-wave LDS RAW: ds queue is in-order per wave)
        #pragma unroll
        for (int ks = 0; ks < 2; ++ks) {
            short8 pa[2], vb2[4];
            #pragma unroll
            for (int pm = 0; pm < 2; ++pm) {
                int row = pm * 16 + lc;
                int byt = (row * 128 + ks * 64 + g * 16) ^ ((row & 7) << 4);
                pa[pm] = *(const short8*)(pw + byt);
            }
            #pragma unroll
            for (int n = 0; n < 4; ++n) {
                int row = n * 16 + lc;
                int byt = (row * 128 + ks * 64 + g * 16) ^ ((row & 7) << 4);
                vb2[n] = *(const short8*)((char*)Vt + byt);
            }
            #pragma unroll
            for (int pm = 0; pm < 2; ++pm)
                #pragma unroll
                for (int n = 0; n < 4; ++n)
                    oacc[pm][n] = __builtin_amdgcn_mfma_f32_16x16x32_bf16(pa[pm], vb2[n], oacc[pm][n], 0, 0, 0);
        }
    }

    // epilogue: O[q][d] — col d = n*16+lc, row q = m*16 + g*4 + r
    #pragma unroll
    for (int m = 0; m < 2; ++m) {
        float inv[4];
        #pragma unroll
        for (int r = 0; r < 4; ++r) inv[r] = 1.0f / lrun[m][r];
        #pragma unroll
        for (int n = 0; n < 4; ++n) {
            int col = (int)hoff + n * 16 + lc;
            #pragma unroll
            for (int r = 0; r < 4; ++r) {
                int row = q0 + w * 32 + m * 16 + g * 4 + r;
                O[(bT + row) * C_ + col] = f2bf(oacc[m][n][r] * inv[r]);
            }
        }
    }
}

extern "C" void kernel_launch(void* const* d_in, const int* in_sizes, int n_in,
                              void* d_out, int out_size, void* d_ws, size_t ws_size,
                              hipStream_t stream) {
    const float* x   = (const float*)d_in[0];
    const float* Wq  = (const float*)d_in[1];
    const float* bq  = (const float*)d_in[2];
    const float* Wk  = (const float*)d_in[3];
    const float* bk  = (const float*)d_in[4];
    const float* Wv  = (const float*)d_in[5];
    const float* bv  = (const float*)d_in[6];
    const float* Wo  = (const float*)d_in[7];
    const float* bo  = (const float*)d_in[8];
    const float* g1  = (const float*)d_in[9];
    const float* b1  = (const float*)d_in[10];
    const float* g2  = (const float*)d_in[11];
    const float* b2  = (const float*)d_in[12];
    const float* W1  = (const float*)d_in[13];
    const float* bm1 = (const float*)d_in[14];
    const float* W2  = (const float*)d_in[15];
    const float* bm2 = (const float*)d_in[16];
    float* out = (float*)d_out;

    const size_t S = (size_t)B_ * T_ * C_;   // 6,291,456 elems
    char* base = (char*)d_ws;
    // bytes: ln1h/o bf16 [0,2S) | q bf16 [2S,4S) | k bf16 [4S,6S) | v bf16 [6S,8S)
    //        hid bf16 (4S el) [4S,12S) | xmid f32 [12S,16S) | weights bf16 [16S,..)
    unsigned short* ln1h = (unsigned short*)base;
    unsigned short* qb   = (unsigned short*)(base + 2 * S);
    unsigned short* kb   = (unsigned short*)(base + 4 * S);
    unsigned short* vb2  = (unsigned short*)(base + 6 * S);
    unsigned short* o    = ln1h;
    unsigned short* ln2h = qb;
    unsigned short* hid  = (unsigned short*)(base + 4 * S);
    float* xmid          = (float*)(base + 12 * S);
    unsigned short* wqt  = (unsigned short*)(base + 16 * S);
    unsigned short* wkt  = wqt + (size_t)C_ * C_;
    unsigned short* wvt  = wkt + (size_t)C_ * C_;
    unsigned short* wot  = wvt + (size_t)C_ * C_;
    unsigned short* w1t  = wot + (size_t)C_ * C_;
    unsigned short* w2t  = w1t + (size_t)C_ * 4 * C_;

    const int M = B_ * T_;
    dim3 blk(256);

    transpose_bf16<<<dim3(C_ / 64, C_ / 64), blk, 0, stream>>>(Wq, wqt, C_, C_);
    transpose_bf16<<<dim3(C_ / 64, C_ / 64), blk, 0, stream>>>(Wk, wkt, C_, C_);
    transpose_bf16<<<dim3(C_ / 64, C_ / 64), blk, 0, stream>>>(Wv, wvt, C_, C_);
    transpose_bf16<<<dim3(C_ / 64, C_ / 64), blk, 0, stream>>>(Wo, wot, C_, C_);
    transpose_bf16<<<dim3(4 * C_ / 64, C_ / 64), blk, 0, stream>>>(W1, w1t, C_, 4 * C_);
    transpose_bf16<<<dim3(C_ / 64, 4 * C_ / 64), blk, 0, stream>>>(W2, w2t, 4 * C_, C_);

    ln_f32_bf16<<<dim3(M), blk, 0, stream>>>(x, g1, b1, ln1h);

    dim3 g_cc(C_ / 128, M / 128);
    dim3 g_c4(4 * C_ / 128, M / 128);
    gemm_bf16<3><<<g_cc, blk, 0, stream>>>(ln1h, wqt, bq, nullptr, qb, M, C_, C_);
    gemm_bf16<3><<<g_cc, blk, 0, stream>>>(ln1h, wkt, bk, nullptr, kb, M, C_, C_);
    gemm_bf16<3><<<g_cc, blk, 0, stream>>>(ln1h, wvt, bv, nullptr, vb2, M, C_, C_);

    attn_mfma<<<dim3(B_ * H_ * (T_ / 128)), blk, 0, stream>>>(qb, kb, vb2, o);

    gemm_bf16<2><<<g_cc, blk, 0, stream>>>(o, wot, bo, x, xmid, M, C_, C_);
    ln_f32_bf16<<<dim3(M), blk, 0, stream>>>(xmid, g2, b2, ln2h);
    gemm_bf16<1><<<g_c4, blk, 0, stream>>>(ln2h, w1t, bm1, nullptr, hid, M, 4 * C_, C_);
    gemm_bf16<2><<<g_cc, blk, 0, stream>>>(hid, w2t, bm2, xmid, out, M, C_, 4 * C_);
}

// Round 5
// 389.014 us; speedup vs baseline: 19.4475x; 1.2389x over previous
//
#include <hip/hip_runtime.h>
#include <hip/hip_bf16.h>

#define B_ 4
#define T_ 2048
#define C_ 768
#define H_ 12
#define D_ 64
#define QS_ 2304   // packed qkv row stride

typedef __attribute__((ext_vector_type(8))) short short8;
typedef __attribute__((ext_vector_type(4))) short short4v;
typedef __attribute__((ext_vector_type(4))) float f32x4;

__device__ __forceinline__ unsigned short f2bf(float f) {
    __hip_bfloat16 h = __float2bfloat16(f);
    return *reinterpret_cast<unsigned short*>(&h);
}

__device__ __forceinline__ void gl_lds16(const void* g, void* l) {
    __builtin_amdgcn_global_load_lds((const __attribute__((address_space(1))) unsigned int*)g,
                                     (__attribute__((address_space(3))) unsigned int*)l,
                                     16, 0, 0);
}

// ---------------- LayerNorm: fp32 in, bf16 out ----------------
__global__ __launch_bounds__(256) void ln_f32_bf16(const float* __restrict__ x,
                                                   const float* __restrict__ g,
                                                   const float* __restrict__ b,
                                                   unsigned short* __restrict__ out) {
    int row = blockIdx.x;
    int tid = threadIdx.x;
    const float* xr = x + (size_t)row * C_;
    float v0 = xr[tid], v1 = xr[tid + 256], v2 = xr[tid + 512];
    float s = v0 + v1 + v2;
    #pragma unroll
    for (int off = 1; off < 64; off <<= 1) s += __shfl_xor(s, off);
    __shared__ float ws1[4], ws2[4];
    int wid = tid >> 6, lane = tid & 63;
    if (lane == 0) ws1[wid] = s;
    __syncthreads();
    float mean = (ws1[0] + ws1[1] + ws1[2] + ws1[3]) * (1.0f / C_);
    float d0 = v0 - mean, d1 = v1 - mean, d2 = v2 - mean;
    float qs = d0*d0 + d1*d1 + d2*d2;
    #pragma unroll
    for (int off = 1; off < 64; off <<= 1) qs += __shfl_xor(qs, off);
    if (lane == 0) ws2[wid] = qs;
    __syncthreads();
    float var = (ws2[0] + ws2[1] + ws2[2] + ws2[3]) * (1.0f / C_);
    float rs = rsqrtf(var + 1e-5f);
    unsigned short* orow = out + (size_t)row * C_;
    orow[tid]       = f2bf(d0 * rs * g[tid]       + b[tid]);
    orow[tid + 256] = f2bf(d1 * rs * g[tid + 256] + b[tid + 256]);
    orow[tid + 512] = f2bf(d2 * rs * g[tid + 512] + b[tid + 512]);
}

// ---------------- transpose + fp32->bf16 convert: Wt[n][k] = W[k][n] ----------------
__global__ __launch_bounds__(256) void transpose_bf16(const float* __restrict__ W,
                                                      unsigned short* __restrict__ Wt,
                                                      int K, int N) {
    __shared__ float t[64][65];
    int n0 = blockIdx.x * 64, k0 = blockIdx.y * 64;
    int r = threadIdx.x >> 4, c4 = (threadIdx.x & 15) * 4;
    #pragma unroll
    for (int i = 0; i < 4; ++i) {
        float4 v = *(const float4*)(W + (size_t)(k0 + i * 16 + r) * N + n0 + c4);
        t[i*16 + r][c4 + 0] = v.x;
        t[i*16 + r][c4 + 1] = v.y;
        t[i*16 + r][c4 + 2] = v.z;
        t[i*16 + r][c4 + 3] = v.w;
    }
    __syncthreads();
    #pragma unroll
    for (int i = 0; i < 4; ++i) {
        ushort4 o;
        o.x = f2bf(t[c4 + 0][i*16 + r]);
        o.y = f2bf(t[c4 + 1][i*16 + r]);
        o.z = f2bf(t[c4 + 2][i*16 + r]);
        o.w = f2bf(t[c4 + 3][i*16 + r]);
        *(ushort4*)(Wt + (size_t)(n0 + i * 16 + r) * K + k0 + c4) = o;
    }
}

// ---------------- concat 3 bias vectors ----------------
__global__ __launch_bounds__(256) void concat3(const float* __restrict__ a,
                                               const float* __restrict__ b,
                                               const float* __restrict__ c,
                                               float* __restrict__ o) {
    int i = blockIdx.x * 256 + threadIdx.x;   // 2304 total
    o[i] = (i < 768) ? a[i] : (i < 1536) ? b[i - 768] : c[i - 1536];
}

// ---------------- bf16 MFMA GEMM: C = A @ Bt^T + bias ----------------
// EPI: 1 = gelu -> bf16 out, 2 = +resid -> fp32 out, 3 = bf16 out
template <int EPI>
__global__ __launch_bounds__(256) void gemm_bf16(const unsigned short* __restrict__ A,
                                                 const unsigned short* __restrict__ Bt,
                                                 const float* __restrict__ bias,
                                                 const float* __restrict__ resid,
                                                 void* __restrict__ Cout,
                                                 int M, int N, int K) {
    __shared__ short As[128 * 32];
    __shared__ short Bs[128 * 32];
    int tid = threadIdx.x;
    int w = tid >> 6, l = tid & 63;
    int bn = blockIdx.x, bm = blockIdx.y;
    int wr = w >> 1, wc = w & 1;

    f32x4 acc[4][4];
    #pragma unroll
    for (int m = 0; m < 4; ++m)
        #pragma unroll
        for (int n = 0; n < 4; ++n)
            acc[m][n] = (f32x4){0.f, 0.f, 0.f, 0.f};

    const short* Ag = (const short*)A + (size_t)(bm * 128) * K;
    const short* Bg = (const short*)Bt + (size_t)(bn * 128) * K;
    int srow = tid >> 2;
    int scol = (tid & 3) * 8;
    int lrow = l & 15, lk = (l >> 4) * 8;

    int nk = K / 32;
    for (int kt = 0; kt < nk; ++kt) {
        int k0 = kt * 32;
        if (kt > 0) __syncthreads();
        #pragma unroll
        for (int i = 0; i < 2; ++i) {
            gl_lds16(Ag + (size_t)(i * 64 + srow) * K + k0 + scol,
                     (char*)As + i * 4096 + w * 1024);
            gl_lds16(Bg + (size_t)(i * 64 + srow) * K + k0 + scol,
                     (char*)Bs + i * 4096 + w * 1024);
        }
        __syncthreads();

        short8 av[4], bv[4];
        #pragma unroll
        for (int m = 0; m < 4; ++m)
            av[m] = *(const short8*)&As[(wr * 64 + m * 16 + lrow) * 32 + lk];
        #pragma unroll
        for (int n = 0; n < 4; ++n)
            bv[n] = *(const short8*)&Bs[(wc * 64 + n * 16 + lrow) * 32 + lk];
        #pragma unroll
        for (int m = 0; m < 4; ++m)
            #pragma unroll
            for (int n = 0; n < 4; ++n)
                acc[m][n] = __builtin_amdgcn_mfma_f32_16x16x32_bf16(av[m], bv[n], acc[m][n], 0, 0, 0);
    }

    int lcol = l & 15, lr4 = (l >> 4) * 4;
    int row0 = bm * 128 + wr * 64;
    int col0 = bn * 128 + wc * 64;
    #pragma unroll
    for (int m = 0; m < 4; ++m) {
        #pragma unroll
        for (int n = 0; n < 4; ++n) {
            int col = col0 + n * 16 + lcol;
            float bz = bias[col];
            #pragma unroll
            for (int r = 0; r < 4; ++r) {
                int row = row0 + m * 16 + lr4 + r;
                float v = acc[m][n][r] + bz;
                if (EPI == 1) {
                    // fast tanh-GELU: v * sigmoid(2*0.79788456*(v+0.044715 v^3))
                    float u = fmaf(0.044715f * v, v * v, v);
                    float e = __builtin_amdgcn_exp2f(u * -2.3022127f);
                    v = v * __builtin_amdgcn_rcpf(1.0f + e);
                    ((unsigned short*)Cout)[(size_t)row * N + col] = f2bf(v);
                } else if (EPI == 2) {
                    v += resid[(size_t)row * N + col];
                    ((float*)Cout)[(size_t)row * N + col] = v;
                } else {
                    ((unsigned short*)Cout)[(size_t)row * N + col] = f2bf(v);
                }
            }
        }
    }
}

// ---------------- MFMA flash attention (packed qkv in, bf16 out, causal) ----------------
// 384 uniform blocks: (bh, p) with q-tiles {p, 15-p} -> 17 k-iters each.
// KVBLK=128. Defer-max: common path has no cross-lane reductions.
__global__ __launch_bounds__(256) void attn_mfma(const unsigned short* __restrict__ QKV,
                                                 unsigned short* __restrict__ O) {
    __shared__ short Ks[128 * 64];       // [k][d] swizzled
    __shared__ short Vt[64 * 128];       // [d][k] swizzled
    __shared__ short Ps[4][32 * 128];    // per-wave [q][k] swizzled

    int tid = threadIdx.x;
    int w = tid >> 6, l = tid & 63;
    int g = l >> 4, lc = l & 15;
    // bijective XCD-chunked remap: 384 = 8 * 48
    int wid = (int)(blockIdx.x & 7) * 48 + (int)(blockIdx.x >> 3);
    int bh = wid >> 3, p = wid & 7;
    int b = bh / H_, h = bh % H_;
    const size_t bT = (size_t)b * T_;
    const unsigned short* Qp = QKV + h * D_;
    const unsigned short* Kp = QKV + 768 + h * D_;
    const unsigned short* Vp = QKV + 1536 + h * D_;

    const float SCL = 0.125f * 1.44269504088896340736f;  // 1/sqrt(D) * log2(e)
    char* pw = (char*)&Ps[w][0];

    for (int half = 0; half < 2; ++half) {
        int qt = half ? (15 - p) : p;
        int q0 = qt * 128;

        short8 qf[2][2];
        #pragma unroll
        for (int m = 0; m < 2; ++m) {
            int row = q0 + w * 32 + m * 16 + lc;
            const unsigned short* qp = Qp + (bT + row) * QS_;
            #pragma unroll
            for (int ks = 0; ks < 2; ++ks)
                qf[m][ks] = *(const short8*)(qp + ks * 32 + g * 8);
        }

        f32x4 oacc[2][4];
        float mrun[2][4], lpart[2][4];
        #pragma unroll
        for (int m = 0; m < 2; ++m) {
            #pragma unroll
            for (int n = 0; n < 4; ++n) oacc[m][n] = (f32x4){0.f, 0.f, 0.f, 0.f};
            #pragma unroll
            for (int r = 0; r < 4; ++r) { mrun[m][r] = -INFINITY; lpart[m][r] = 0.f; }
        }

        int ntiles = qt + 1;
        for (int kt = 0; kt < ntiles; ++kt) {
            int k0 = kt * 128;
            if (half | kt) __syncthreads();
            // stage K [128][64]
            #pragma unroll
            for (int pass = 0; pass < 4; ++pass) {
                int kk = pass * 32 + (tid >> 3);
                int ce = (tid & 7) * 8;
                short8 kv = *(const short8*)(Kp + (bT + k0 + kk) * QS_ + ce);
                int byt = (kk * 128 + ce * 2) ^ ((kk & 7) << 4);
                *(short8*)((char*)Ks + byt) = kv;
            }
            // stage V transposed [64][128]
            {
                int d = l;
                #pragma unroll
                for (int pp = 0; pp < 8; ++pp) {
                    int kk0 = w * 32 + pp * 4;
                    const unsigned short* vp = Vp + (bT + k0 + kk0) * QS_ + d;
                    short4v pk = {(short)vp[0], (short)vp[QS_], (short)vp[2 * QS_], (short)vp[3 * QS_]};
                    int byt = (d * 256 + kk0 * 2) ^ ((d & 7) << 4);
                    *(short4v*)((char*)Vt + byt) = pk;
                }
            }
            __syncthreads();

            // S = Q @ K^T  (raw, scale folded into exp)
            f32x4 sacc[2][8];
            #pragma unroll
            for (int m = 0; m < 2; ++m)
                #pragma unroll
                for (int n = 0; n < 8; ++n) sacc[m][n] = (f32x4){0.f, 0.f, 0.f, 0.f};
            __builtin_amdgcn_s_setprio(1);
            #pragma unroll
            for (int ks = 0; ks < 2; ++ks) {
                short8 bv[8];
                #pragma unroll
                for (int n = 0; n < 8; ++n) {
                    int row = n * 16 + lc;
                    int byt = (row * 128 + ks * 64 + g * 16) ^ ((row & 7) << 4);
                    bv[n] = *(const short8*)((char*)Ks + byt);
                }
                #pragma unroll
                for (int m = 0; m < 2; ++m)
                    #pragma unroll
                    for (int n = 0; n < 8; ++n)
                        sacc[m][n] = __builtin_amdgcn_mfma_f32_16x16x32_bf16(qf[m][ks], bv[n], sacc[m][n], 0, 0, 0);
            }
            __builtin_amdgcn_s_setprio(0);

            // causal mask (raw -inf), partial tiles only
            bool full = (k0 + 127 <= q0 + w * 32);
            if (!full) {
                #pragma unroll
                for (int m = 0; m < 2; ++m)
                    #pragma unroll
                    for (int n = 0; n < 8; ++n) {
                        int col = k0 + n * 16 + lc;
                        #pragma unroll
                        for (int r = 0; r < 4; ++r)
                            if (col > q0 + w * 32 + m * 16 + g * 4 + r) sacc[m][n][r] = -INFINITY;
                    }
            }

            // local max per row (scaled)
            float lmax[2][4];
            #pragma unroll
            for (int m = 0; m < 2; ++m)
                #pragma unroll
                for (int r = 0; r < 4; ++r) {
                    float a0 = fmaxf(fmaxf(sacc[m][0][r], sacc[m][1][r]),
                                     fmaxf(sacc[m][2][r], sacc[m][3][r]));
                    float a1 = fmaxf(fmaxf(sacc[m][4][r], sacc[m][5][r]),
                                     fmaxf(sacc[m][6][r], sacc[m][7][r]));
                    lmax[m][r] = fmaxf(a0, a1) * SCL;
                }
            int okl = 1;
            #pragma unroll
            for (int m = 0; m < 2; ++m)
                #pragma unroll
                for (int r = 0; r < 4; ++r)
                    okl &= (lmax[m][r] <= mrun[m][r] + 8.0f);

            if (__all(okl)) {
                // defer path: no shuffles, no rescale
                #pragma unroll
                for (int m = 0; m < 2; ++m)
                    #pragma unroll
                    for (int r = 0; r < 4; ++r) {
                        float mm = mrun[m][r];
                        float rs = 0.f;
                        #pragma unroll
                        for (int n = 0; n < 8; ++n) {
                            float pv = __builtin_amdgcn_exp2f(fmaf(sacc[m][n][r], SCL, -mm));
                            sacc[m][n][r] = pv;
                            rs += pv;
                        }
                        lpart[m][r] += rs;
                    }
            } else {
                #pragma unroll
                for (int m = 0; m < 2; ++m)
                    #pragma unroll
                    for (int r = 0; r < 4; ++r) {
                        float rm = lmax[m][r];
                        #pragma unroll
                        for (int off = 1; off < 16; off <<= 1) rm = fmaxf(rm, __shfl_xor(rm, off));
                        float mnew = fmaxf(mrun[m][r], rm);
                        float sc = __builtin_amdgcn_exp2f(mrun[m][r] - mnew);
                        mrun[m][r] = mnew;
                        float rs = 0.f;
                        #pragma unroll
                        for (int n = 0; n < 8; ++n) {
                            float pv = __builtin_amdgcn_exp2f(fmaf(sacc[m][n][r], SCL, -mnew));
                            sacc[m][n][r] = pv;
                            rs += pv;
                        }
                        lpart[m][r] = lpart[m][r] * sc + rs;
                        #pragma unroll
                        for (int n = 0; n < 4; ++n) oacc[m][n][r] *= sc;
                    }
            }

            // write P bf16 to per-wave swizzled LDS [32][128]
            #pragma unroll
            for (int m = 0; m < 2; ++m)
                #pragma unroll
                for (int n = 0; n < 8; ++n)
                    #pragma unroll
                    for (int r = 0; r < 4; ++r) {
                        int prow = m * 16 + g * 4 + r;
                        int byt = (prow * 256 + (n * 16 + lc) * 2) ^ ((prow & 7) << 4);
                        *(unsigned short*)(pw + byt) = f2bf(sacc[m][n][r]);
                    }

            // O += P @ V (same-wave LDS RAW, in-order)
            __builtin_amdgcn_s_setprio(1);
            #pragma unroll
            for (int ks = 0; ks < 4; ++ks) {
                short8 pa[2], vb2[4];
                #pragma unroll
                for (int pm = 0; pm < 2; ++pm) {
                    int row = pm * 16 + lc;
                    int byt = (row * 256 + ks * 64 + g * 16) ^ ((row & 7) << 4);
                    pa[pm] = *(const short8*)(pw + byt);
                }
                #pragma unroll
                for (int n = 0; n < 4; ++n) {
                    int row = n * 16 + lc;
                    int byt = (row * 256 + ks * 64 + g * 16) ^ ((row & 7) << 4);
                    vb2[n] = *(const short8*)((char*)Vt + byt);
                }
                #pragma unroll
                for (int pm = 0; pm < 2; ++pm)
                    #pragma unroll
                    for (int n = 0; n < 4; ++n)
                        oacc[pm][n] = __builtin_amdgcn_mfma_f32_16x16x32_bf16(pa[pm], vb2[n], oacc[pm][n], 0, 0, 0);
            }
            __builtin_amdgcn_s_setprio(0);
        }

        // epilogue: reduce lpart across 16 lanes, write O
        #pragma unroll
        for (int m = 0; m < 2; ++m) {
            float inv[4];
            #pragma unroll
            for (int r = 0; r < 4; ++r) {
                float lv = lpart[m][r];
                #pragma unroll
                for (int off = 1; off < 16; off <<= 1) lv += __shfl_xor(lv, off);
                inv[r] = 1.0f / lv;
            }
            #pragma unroll
            for (int n = 0; n < 4; ++n) {
                int col = h * D_ + n * 16 + lc;
                #pragma unroll
                for (int r = 0; r < 4; ++r) {
                    int row = q0 + w * 32 + m * 16 + g * 4 + r;
                    O[(bT + row) * C_ + col] = f2bf(oacc[m][n][r] * inv[r]);
                }
            }
        }
    }
}

extern "C" void kernel_launch(void* const* d_in, const int* in_sizes, int n_in,
                              void* d_out, int out_size, void* d_ws, size_t ws_size,
                              hipStream_t stream) {
    const float* x   = (const float*)d_in[0];
    const float* Wq  = (const float*)d_in[1];
    const float* bq  = (const float*)d_in[2];
    const float* Wk  = (const float*)d_in[3];
    const float* bk  = (const float*)d_in[4];
    const float* Wv  = (const float*)d_in[5];
    const float* bv  = (const float*)d_in[6];
    const float* Wo  = (const float*)d_in[7];
    const float* bo  = (const float*)d_in[8];
    const float* g1  = (const float*)d_in[9];
    const float* b1  = (const float*)d_in[10];
    const float* g2  = (const float*)d_in[11];
    const float* b2  = (const float*)d_in[12];
    const float* W1  = (const float*)d_in[13];
    const float* bm1 = (const float*)d_in[14];
    const float* W2  = (const float*)d_in[15];
    const float* bm2 = (const float*)d_in[16];
    float* out = (float*)d_out;

    const size_t S = (size_t)B_ * T_ * C_;   // 6,291,456 elems
    char* base = (char*)d_ws;
    // bytes: ln1h/o bf16 [0,2S) | qkv bf16 [2S,8S) | ln2h bf16 [2S,4S) after attn |
    //        hid bf16 [4S,12S) | xmid f32 [12S,16S) | weights [16S,...)
    unsigned short* ln1h = (unsigned short*)base;
    unsigned short* qkvb = (unsigned short*)(base + 2 * S);
    unsigned short* o    = ln1h;
    unsigned short* ln2h = qkvb;
    unsigned short* hid  = (unsigned short*)(base + 4 * S);
    float* xmid          = (float*)(base + 12 * S);
    unsigned short* wqkvt = (unsigned short*)(base + 16 * S);      // [2304][768]
    unsigned short* wot   = wqkvt + (size_t)3 * C_ * C_;
    unsigned short* w1t   = wot + (size_t)C_ * C_;                 // [3072][768]
    unsigned short* w2t   = w1t + (size_t)C_ * 4 * C_;             // [768][3072]
    float* bqkv           = (float*)(w2t + (size_t)C_ * 4 * C_);   // [2304]

    const int M = B_ * T_;
    dim3 blk(256);

    transpose_bf16<<<dim3(C_ / 64, C_ / 64), blk, 0, stream>>>(Wq, wqkvt, C_, C_);
    transpose_bf16<<<dim3(C_ / 64, C_ / 64), blk, 0, stream>>>(Wk, wqkvt + (size_t)C_ * C_, C_, C_);
    transpose_bf16<<<dim3(C_ / 64, C_ / 64), blk, 0, stream>>>(Wv, wqkvt + (size_t)2 * C_ * C_, C_, C_);
    transpose_bf16<<<dim3(C_ / 64, C_ / 64), blk, 0, stream>>>(Wo, wot, C_, C_);
    transpose_bf16<<<dim3(4 * C_ / 64, C_ / 64), blk, 0, stream>>>(W1, w1t, C_, 4 * C_);
    transpose_bf16<<<dim3(C_ / 64, 4 * C_ / 64), blk, 0, stream>>>(W2, w2t, 4 * C_, C_);
    concat3<<<dim3(9), blk, 0, stream>>>(bq, bk, bv, bqkv);

    ln_f32_bf16<<<dim3(M), blk, 0, stream>>>(x, g1, b1, ln1h);

    gemm_bf16<3><<<dim3(QS_ / 128, M / 128), blk, 0, stream>>>(ln1h, wqkvt, bqkv, nullptr, qkvb, M, QS_, C_);

    attn_mfma<<<dim3(B_ * H_ * 8), blk, 0, stream>>>(qkvb, o);

    gemm_bf16<2><<<dim3(C_ / 128, M / 128), blk, 0, stream>>>(o, wot, bo, x, xmid, M, C_, C_);
    ln_f32_bf16<<<dim3(M), blk, 0, stream>>>(xmid, g2, b2, ln2h);
    gemm_bf16<1><<<dim3(4 * C_ / 128, M / 128), blk, 0, stream>>>(ln2h, w1t, bm1, nullptr, hid, M, 4 * C_, C_);
    gemm_bf16<2><<<dim3(C_ / 128, M / 128), blk, 0, stream>>>(hid, w2t, bm2, xmid, out, M, C_, 4 * C_);
}

// Round 6
// 355.982 us; speedup vs baseline: 21.2521x; 1.0928x over previous
//
#include <hip/hip_runtime.h>
#include <hip/hip_bf16.h>

#define B_ 4
#define T_ 2048
#define C_ 768
#define H_ 12
#define D_ 64
#define QS_ 2304   // packed qkv row stride

typedef __attribute__((ext_vector_type(8))) short short8;
typedef __attribute__((ext_vector_type(4))) short short4v;
typedef __attribute__((ext_vector_type(4))) float f32x4;

__device__ __forceinline__ unsigned short f2bf(float f) {
    __hip_bfloat16 h = __float2bfloat16(f);
    return *reinterpret_cast<unsigned short*>(&h);
}

__device__ __forceinline__ unsigned cvt_pk_bf16(float lo, float hi) {
    unsigned r;
    asm("v_cvt_pk_bf16_f32 %0, %1, %2" : "=v"(r) : "v"(lo), "v"(hi));
    return r;
}

__device__ __forceinline__ void gl_lds16(const void* g, void* l) {
    __builtin_amdgcn_global_load_lds((const __attribute__((address_space(1))) unsigned int*)g,
                                     (__attribute__((address_space(3))) unsigned int*)l,
                                     16, 0, 0);
}

// ---------------- LayerNorm: fp32 in, bf16 out ----------------
__global__ __launch_bounds__(256) void ln_f32_bf16(const float* __restrict__ x,
                                                   const float* __restrict__ g,
                                                   const float* __restrict__ b,
                                                   unsigned short* __restrict__ out) {
    int row = blockIdx.x;
    int tid = threadIdx.x;
    const float* xr = x + (size_t)row * C_;
    float v0 = xr[tid], v1 = xr[tid + 256], v2 = xr[tid + 512];
    float s = v0 + v1 + v2;
    #pragma unroll
    for (int off = 1; off < 64; off <<= 1) s += __shfl_xor(s, off);
    __shared__ float ws1[4], ws2[4];
    int wid = tid >> 6, lane = tid & 63;
    if (lane == 0) ws1[wid] = s;
    __syncthreads();
    float mean = (ws1[0] + ws1[1] + ws1[2] + ws1[3]) * (1.0f / C_);
    float d0 = v0 - mean, d1 = v1 - mean, d2 = v2 - mean;
    float qs = d0*d0 + d1*d1 + d2*d2;
    #pragma unroll
    for (int off = 1; off < 64; off <<= 1) qs += __shfl_xor(qs, off);
    if (lane == 0) ws2[wid] = qs;
    __syncthreads();
    float var = (ws2[0] + ws2[1] + ws2[2] + ws2[3]) * (1.0f / C_);
    float rs = rsqrtf(var + 1e-5f);
    unsigned short* orow = out + (size_t)row * C_;
    orow[tid]       = f2bf(d0 * rs * g[tid]       + b[tid]);
    orow[tid + 256] = f2bf(d1 * rs * g[tid + 256] + b[tid + 256]);
    orow[tid + 512] = f2bf(d2 * rs * g[tid + 512] + b[tid + 512]);
}

// ---------------- transpose + fp32->bf16 convert: Wt[n][k] = W[k][n] ----------------
__global__ __launch_bounds__(256) void transpose_bf16(const float* __restrict__ W,
                                                      unsigned short* __restrict__ Wt,
                                                      int K, int N) {
    __shared__ float t[64][65];
    int n0 = blockIdx.x * 64, k0 = blockIdx.y * 64;
    int r = threadIdx.x >> 4, c4 = (threadIdx.x & 15) * 4;
    #pragma unroll
    for (int i = 0; i < 4; ++i) {
        float4 v = *(const float4*)(W + (size_t)(k0 + i * 16 + r) * N + n0 + c4);
        t[i*16 + r][c4 + 0] = v.x;
        t[i*16 + r][c4 + 1] = v.y;
        t[i*16 + r][c4 + 2] = v.z;
        t[i*16 + r][c4 + 3] = v.w;
    }
    __syncthreads();
    #pragma unroll
    for (int i = 0; i < 4; ++i) {
        ushort4 o;
        o.x = f2bf(t[c4 + 0][i*16 + r]);
        o.y = f2bf(t[c4 + 1][i*16 + r]);
        o.z = f2bf(t[c4 + 2][i*16 + r]);
        o.w = f2bf(t[c4 + 3][i*16 + r]);
        *(ushort4*)(Wt + (size_t)(n0 + i * 16 + r) * K + k0 + c4) = o;
    }
}

// ---------------- concat 3 bias vectors ----------------
__global__ __launch_bounds__(256) void concat3(const float* __restrict__ a,
                                               const float* __restrict__ b,
                                               const float* __restrict__ c,
                                               float* __restrict__ o) {
    int i = blockIdx.x * 256 + threadIdx.x;   // 2304 total
    o[i] = (i < 768) ? a[i] : (i < 1536) ? b[i - 768] : c[i - 1536];
}

// ---------------- bf16 MFMA GEMM: C = A @ Bt^T + bias ----------------
// 1D grid with bijective XCD-chunked remap (grid % 8 == 0 required).
// EPI: 1 = gelu -> bf16 out, 2 = +resid -> fp32 out, 3 = bf16 out
template <int EPI>
__global__ __launch_bounds__(256) void gemm_bf16(const unsigned short* __restrict__ A,
                                                 const unsigned short* __restrict__ Bt,
                                                 const float* __restrict__ bias,
                                                 const float* __restrict__ resid,
                                                 void* __restrict__ Cout,
                                                 int M, int N, int K, int gx) {
    __shared__ short As[128 * 32];
    __shared__ short Bs[128 * 32];
    int tid = threadIdx.x;
    int w = tid >> 6, l = tid & 63;
    int nb = gridDim.x;
    int per = nb >> 3;
    int fid = (int)blockIdx.x;
    int wid = (fid & 7) * per + (fid >> 3);
    int bn = wid % gx, bm = wid / gx;
    int wr = w >> 1, wc = w & 1;

    f32x4 acc[4][4];
    #pragma unroll
    for (int m = 0; m < 4; ++m)
        #pragma unroll
        for (int n = 0; n < 4; ++n)
            acc[m][n] = (f32x4){0.f, 0.f, 0.f, 0.f};

    const short* Ag = (const short*)A + (size_t)(bm * 128) * K;
    const short* Bg = (const short*)Bt + (size_t)(bn * 128) * K;
    int srow = tid >> 2;
    int scol = (tid & 3) * 8;
    int lrow = l & 15, lk = (l >> 4) * 8;

    int nk = K / 32;
    for (int kt = 0; kt < nk; ++kt) {
        int k0 = kt * 32;
        if (kt > 0) __syncthreads();
        #pragma unroll
        for (int i = 0; i < 2; ++i) {
            gl_lds16(Ag + (size_t)(i * 64 + srow) * K + k0 + scol,
                     (char*)As + i * 4096 + w * 1024);
            gl_lds16(Bg + (size_t)(i * 64 + srow) * K + k0 + scol,
                     (char*)Bs + i * 4096 + w * 1024);
        }
        __syncthreads();

        short8 av[4], bv[4];
        #pragma unroll
        for (int m = 0; m < 4; ++m)
            av[m] = *(const short8*)&As[(wr * 64 + m * 16 + lrow) * 32 + lk];
        #pragma unroll
        for (int n = 0; n < 4; ++n)
            bv[n] = *(const short8*)&Bs[(wc * 64 + n * 16 + lrow) * 32 + lk];
        #pragma unroll
        for (int m = 0; m < 4; ++m)
            #pragma unroll
            for (int n = 0; n < 4; ++n)
                acc[m][n] = __builtin_amdgcn_mfma_f32_16x16x32_bf16(av[m], bv[n], acc[m][n], 0, 0, 0);
    }

    int lcol = l & 15, lr4 = (l >> 4) * 4;
    int row0 = bm * 128 + wr * 64;
    int col0 = bn * 128 + wc * 64;
    #pragma unroll
    for (int m = 0; m < 4; ++m) {
        #pragma unroll
        for (int n = 0; n < 4; ++n) {
            int col = col0 + n * 16 + lcol;
            float bz = bias[col];
            #pragma unroll
            for (int r = 0; r < 4; ++r) {
                int row = row0 + m * 16 + lr4 + r;
                float v = acc[m][n][r] + bz;
                if (EPI == 1) {
                    float u = fmaf(0.044715f * v, v * v, v);
                    float e = __builtin_amdgcn_exp2f(u * -2.3022127f);
                    v = v * __builtin_amdgcn_rcpf(1.0f + e);
                    ((unsigned short*)Cout)[(size_t)row * N + col] = f2bf(v);
                } else if (EPI == 2) {
                    v += resid[(size_t)row * N + col];
                    ((float*)Cout)[(size_t)row * N + col] = v;
                } else {
                    ((unsigned short*)Cout)[(size_t)row * N + col] = f2bf(v);
                }
            }
        }
    }
}

// ---------------- MFMA flash attention v3 (swapped QK^T, in-register P) ----------------
// 768 blocks = 48 bh * 16 pairs; pair (a, 31-a) of 64-row q-tiles -> uniform work.
// 4 waves x 16 q-rows. KVBLK=128. S^T = mfma(K, Q): lane owns one q-column ->
// lane-local softmax (exp vs running ref mrun, post-fix on rare violation).
// P stays in registers: cvt_pk quads + 4-lane-group shuffles build PV A-frags.
__global__ __launch_bounds__(256) void attn_mfma3(const unsigned short* __restrict__ QKV,
                                                  unsigned short* __restrict__ O) {
    __shared__ short Ks[128 * 64];   // [k][d], byte ^= (k&7)<<4
    __shared__ short Vt[64 * 128];   // [d][k], byte ^= (d&7)<<4

    int tid = threadIdx.x;
    int w = tid >> 6, l = tid & 63;
    int g = l >> 4, lc = l & 15;
    // bijective XCD remap: 768 = 8 * 96
    int wid = (int)(blockIdx.x & 7) * 96 + (int)(blockIdx.x >> 3);
    int bh = wid >> 4, pi = wid & 15;
    int b = bh / H_, h = bh % H_;
    const size_t bT = (size_t)b * T_;
    const unsigned short* Qp = QKV + h * D_;
    const unsigned short* Kp = QKV + 768 + h * D_;
    const unsigned short* Vp = QKV + 1536 + h * D_;
    const float SCL = 0.125f * 1.44269504088896340736f;  // 1/sqrt(D) * log2(e)

    for (int half = 0; half < 2; ++half) {
        int a = half ? pi : (31 - pi);   // heavy q-tile first
        int q0 = a * 64;
        int qw = q0 + w * 16;            // wave's q rows: qw..qw+15

        // Q B-fragments (col q = qw+lc, k-dim = d)
        short8 qf[2];
        {
            const unsigned short* qp = Qp + (bT + qw + lc) * QS_;
            qf[0] = *(const short8*)(qp + g * 8);
            qf[1] = *(const short8*)(qp + 32 + g * 8);
        }

        f32x4 oacc[4];
        #pragma unroll
        for (int n = 0; n < 4; ++n) oacc[n] = (f32x4){0.f, 0.f, 0.f, 0.f};
        float mrun = 4.0f, lpart = 0.f;

        int ntiles = (a >> 1) + 1;
        for (int kt = 0; kt < ntiles; ++kt) {
            int k0 = kt * 128;
            if (half | kt) __syncthreads();
            // --- stage K [128][64] via global_load_lds, pre-swizzled source ---
            #pragma unroll
            for (int c = 0; c < 4; ++c) {
                int row = w * 32 + c * 8 + (l >> 3);
                int inner = (l & 7) * 16;
                const char* src = (const char*)(Kp + (bT + k0 + row) * QS_)
                                  + (inner ^ ((row & 7) << 4));
                gl_lds16(src, (char*)Ks + w * 4096 + c * 1024);
            }
            // --- stage V transposed [64][128]; 16-lane groups write consecutive d ---
            #pragma unroll
            for (int dblk = 0; dblk < 4; ++dblk)
                #pragma unroll
                for (int pp = 0; pp < 2; ++pp) {
                    int d = lc + dblk * 16;
                    int kk0 = w * 32 + g * 4 + pp * 16;
                    const unsigned short* vp = Vp + (bT + k0 + kk0) * QS_ + d;
                    short4v pk = {(short)vp[0], (short)vp[QS_], (short)vp[2*QS_], (short)vp[3*QS_]};
                    int byt = (d * 256 + kk0 * 2) ^ ((d & 7) << 4);
                    *(short4v*)((char*)Vt + byt) = pk;
                }
            __syncthreads();

            // --- S^T = K @ Q^T per 16-k frag; immediate exp with mrun ref ---
            uint2 qd[8];
            float lmax = -INFINITY;
            float rsum = 0.f;
            bool full = (k0 + 127 <= qw);
            #pragma unroll
            for (int mk = 0; mk < 8; ++mk) {
                f32x4 s = (f32x4){0.f, 0.f, 0.f, 0.f};
                __builtin_amdgcn_s_setprio(1);
                #pragma unroll
                for (int ksd = 0; ksd < 2; ++ksd) {
                    int row = mk * 16 + lc;
                    int byt = (row * 128 + ksd * 64 + g * 16) ^ ((row & 7) << 4);
                    short8 av = *(const short8*)((char*)Ks + byt);
                    s = __builtin_amdgcn_mfma_f32_16x16x32_bf16(av, qf[ksd], s, 0, 0, 0);
                }
                __builtin_amdgcn_s_setprio(0);
                // lane holds S^T[k = k0+mk*16+g*4+r][q = qw+lc]
                float p[4];
                #pragma unroll
                for (int r = 0; r < 4; ++r) {
                    float sv = s[r] * SCL;
                    if (!full && (k0 + mk * 16 + g * 4 + r > qw + lc)) sv = -INFINITY;
                    lmax = fmaxf(lmax, sv);
                    float pv = __builtin_amdgcn_exp2f(sv - mrun);
                    p[r] = pv;
                    rsum += pv;
                }
                qd[mk].x = cvt_pk_bf16(p[0], p[1]);
                qd[mk].y = cvt_pk_bf16(p[2], p[3]);
            }
            lpart += rsum;

            // --- PV: assemble A-frags via 4-lane-group shuffles, MFMA with Vt ---
            #pragma unroll
            for (int ks = 0; ks < 4; ++ks) {
                uint2 qa = qd[ks * 2], qb = qd[ks * 2 + 1];
                int srcLo = lc + ((g & 1) << 5);
                int srcHi = srcLo + 16;
                unsigned a0 = (unsigned)__shfl((int)qa.x, srcLo);
                unsigned a1 = (unsigned)__shfl((int)qa.y, srcLo);
                unsigned a2 = (unsigned)__shfl((int)qa.x, srcHi);
                unsigned a3 = (unsigned)__shfl((int)qa.y, srcHi);
                unsigned b0 = (unsigned)__shfl((int)qb.x, srcLo);
                unsigned b1 = (unsigned)__shfl((int)qb.y, srcLo);
                unsigned b2 = (unsigned)__shfl((int)qb.x, srcHi);
                unsigned b3 = (unsigned)__shfl((int)qb.y, srcHi);
                bool lo = (g < 2);
                union { unsigned u[4]; short8 s8; } pa;
                pa.u[0] = lo ? a0 : b0;
                pa.u[1] = lo ? a1 : b1;
                pa.u[2] = lo ? a2 : b2;
                pa.u[3] = lo ? a3 : b3;
                short8 vbv[4];
                #pragma unroll
                for (int n = 0; n < 4; ++n) {
                    int row = n * 16 + lc;
                    int byt = (row * 256 + ks * 64 + g * 16) ^ ((row & 7) << 4);
                    vbv[n] = *(const short8*)((char*)Vt + byt);
                }
                __builtin_amdgcn_s_setprio(1);
                #pragma unroll
                for (int n = 0; n < 4; ++n)
                    oacc[n] = __builtin_amdgcn_mfma_f32_16x16x32_bf16(pa.s8, vbv[n], oacc[n], 0, 0, 0);
                __builtin_amdgcn_s_setprio(0);
            }

            // --- rare violation fix: one common scale repairs oacc & lpart ---
            if (__any(lmax > mrun + 8.0f)) {
                lmax = fmaxf(lmax, __shfl_xor(lmax, 16));
                lmax = fmaxf(lmax, __shfl_xor(lmax, 32));
                float mnew = fmaxf(mrun, lmax);
                float cc = __builtin_amdgcn_exp2f(mrun - mnew);
                lpart *= cc;
                mrun = mnew;
                #pragma unroll
                for (int r = 0; r < 4; ++r) {
                    float cr = __shfl(cc, (l & 48) + g * 4 + r);
                    #pragma unroll
                    for (int n = 0; n < 4; ++n) oacc[n][r] *= cr;
                }
            }
        }

        // --- epilogue: group-reduce l, deliver inv to oacc rows, write O ---
        float lv = lpart;
        lv += __shfl_xor(lv, 16);
        lv += __shfl_xor(lv, 32);
        float linv = 1.0f / lv;
        float inv[4];
        #pragma unroll
        for (int r = 0; r < 4; ++r) inv[r] = __shfl(linv, (l & 48) + g * 4 + r);
        #pragma unroll
        for (int n = 0; n < 4; ++n) {
            int col = h * D_ + n * 16 + lc;
            #pragma unroll
            for (int r = 0; r < 4; ++r) {
                int row = qw + g * 4 + r;
                O[(bT + row) * C_ + col] = f2bf(oacc[n][r] * inv[r]);
            }
        }
    }
}

extern "C" void kernel_launch(void* const* d_in, const int* in_sizes, int n_in,
                              void* d_out, int out_size, void* d_ws, size_t ws_size,
                              hipStream_t stream) {
    const float* x   = (const float*)d_in[0];
    const float* Wq  = (const float*)d_in[1];
    const float* bq  = (const float*)d_in[2];
    const float* Wk  = (const float*)d_in[3];
    const float* bk  = (const float*)d_in[4];
    const float* Wv  = (const float*)d_in[5];
    const float* bv  = (const float*)d_in[6];
    const float* Wo  = (const float*)d_in[7];
    const float* bo  = (const float*)d_in[8];
    const float* g1  = (const float*)d_in[9];
    const float* b1  = (const float*)d_in[10];
    const float* g2  = (const float*)d_in[11];
    const float* b2  = (const float*)d_in[12];
    const float* W1  = (const float*)d_in[13];
    const float* bm1 = (const float*)d_in[14];
    const float* W2  = (const float*)d_in[15];
    const float* bm2 = (const float*)d_in[16];
    float* out = (float*)d_out;

    const size_t S = (size_t)B_ * T_ * C_;   // 6,291,456 elems
    char* base = (char*)d_ws;
    unsigned short* ln1h = (unsigned short*)base;
    unsigned short* qkvb = (unsigned short*)(base + 2 * S);
    unsigned short* o    = ln1h;
    unsigned short* ln2h = qkvb;
    unsigned short* hid  = (unsigned short*)(base + 4 * S);
    float* xmid          = (float*)(base + 12 * S);
    unsigned short* wqkvt = (unsigned short*)(base + 16 * S);      // [2304][768]
    unsigned short* wot   = wqkvt + (size_t)3 * C_ * C_;
    unsigned short* w1t   = wot + (size_t)C_ * C_;                 // [3072][768]
    unsigned short* w2t   = w1t + (size_t)C_ * 4 * C_;             // [768][3072]
    float* bqkv           = (float*)(w2t + (size_t)C_ * 4 * C_);   // [2304]

    const int M = B_ * T_;
    dim3 blk(256);

    transpose_bf16<<<dim3(C_ / 64, C_ / 64), blk, 0, stream>>>(Wq, wqkvt, C_, C_);
    transpose_bf16<<<dim3(C_ / 64, C_ / 64), blk, 0, stream>>>(Wk, wqkvt + (size_t)C_ * C_, C_, C_);
    transpose_bf16<<<dim3(C_ / 64, C_ / 64), blk, 0, stream>>>(Wv, wqkvt + (size_t)2 * C_ * C_, C_, C_);
    transpose_bf16<<<dim3(C_ / 64, C_ / 64), blk, 0, stream>>>(Wo, wot, C_, C_);
    transpose_bf16<<<dim3(4 * C_ / 64, C_ / 64), blk, 0, stream>>>(W1, w1t, C_, 4 * C_);
    transpose_bf16<<<dim3(C_ / 64, 4 * C_ / 64), blk, 0, stream>>>(W2, w2t, 4 * C_, C_);
    concat3<<<dim3(9), blk, 0, stream>>>(bq, bk, bv, bqkv);

    ln_f32_bf16<<<dim3(M), blk, 0, stream>>>(x, g1, b1, ln1h);

    // grids as 1D (count % 8 == 0 for the XCD remap); gx passed explicitly
    gemm_bf16<3><<<dim3((QS_ / 128) * (M / 128)), blk, 0, stream>>>(ln1h, wqkvt, bqkv, nullptr, qkvb, M, QS_, C_, QS_ / 128);

    attn_mfma3<<<dim3(B_ * H_ * 16), blk, 0, stream>>>(qkvb, o);

    gemm_bf16<2><<<dim3((C_ / 128) * (M / 128)), blk, 0, stream>>>(o, wot, bo, x, xmid, M, C_, C_, C_ / 128);
    ln_f32_bf16<<<dim3(M), blk, 0, stream>>>(xmid, g2, b2, ln2h);
    gemm_bf16<1><<<dim3((4 * C_ / 128) * (M / 128)), blk, 0, stream>>>(ln2h, w1t, bm1, nullptr, hid, M, 4 * C_, C_, 4 * C_ / 128);
    gemm_bf16<2><<<dim3((C_ / 128) * (M / 128)), blk, 0, stream>>>(hid, w2t, bm2, xmid, out, M, C_, 4 * C_, C_ / 128);
}